// Round 19
// baseline (466.023 us; speedup 1.0000x reference)
//
#include <hip/hip_runtime.h>
#include <math.h>

#define NN 20000
#define NE 320000
#define CC 10000
#define KIN 768
#define NH 8
#define ND 64
#define NHD 512
#define NSA 128
#define NBKT 79                 // buckets of 256 nodes: 79*256 = 20224 >= NN

#define WTB_SZ (NHD * KIN)      // 393216 per graph
#define W1TB_SZ (NSA * NHD)     // 65536 per stage

typedef __attribute__((ext_vector_type(4))) float f32x4;
typedef __attribute__((ext_vector_type(8))) short s16x8;

__device__ __forceinline__ unsigned short f2bf(float f) {
  unsigned u = __float_as_uint(f);
  u += 0x7fffu + ((u >> 16) & 1u);
  return (unsigned short)(u >> 16);
}
__device__ __forceinline__ float bf2f(unsigned short s) {
  return __uint_as_float(((unsigned)s) << 16);
}
__device__ __forceinline__ float bflo(unsigned u) { return __uint_as_float(u << 16); }
__device__ __forceinline__ float bfhi(unsigned u) { return __uint_as_float(u & 0xffff0000u); }

__device__ __forceinline__ void gl_lds16(const void* g, void* l) {
  __builtin_amdgcn_global_load_lds(
      (const __attribute__((address_space(1))) unsigned int*)g,
      (__attribute__((address_space(3))) unsigned int*)l, 16, 0, 0);
}

union u4s8 { uint4 u; s16x8 v; };

// ---------------- prep: all weight transposes + zero deg3 + zero scal ----------------
__global__ void k_prep(const float* __restrict__ W0, const float* __restrict__ W1,
                       const float* __restrict__ W2, const float* __restrict__ sw1,
                       const float* __restrict__ aw1, unsigned short* __restrict__ wtb3,
                       unsigned short* __restrict__ w1tb2, int* __restrict__ deg3,
                       float* __restrict__ scal) {
  int i = blockIdx.x * 256 + threadIdx.x;
  if (i < 3 * WTB_SZ) {
    int g = i / WTB_SZ;
    int j = i - g * WTB_SZ;
    int n = j / KIN, k = j - n * KIN;
    const float* W = (g == 0) ? W0 : (g == 1) ? W1 : W2;
    wtb3[i] = f2bf(W[(size_t)k * NHD + n]);
    return;
  }
  i -= 3 * WTB_SZ;
  if (i < 2 * W1TB_SZ) {
    int p = i / W1TB_SZ;
    int j = i - p * W1TB_SZ;
    int n = j / NHD, k = j - n * NHD;
    const float* W = p ? aw1 : sw1;
    w1tb2[p * W1TB_SZ + n * NHD + k] = f2bf(W[(size_t)k * NSA + n]);
    return;
  }
  i -= 2 * W1TB_SZ;
  if (i < 3 * NN) { deg3[i] = 0; return; }
  i -= 3 * NN;
  if (i < 4) scal[i] = 0.f;
}

// ---------------- GAT GEMM: hb[M,512](bf16) = A[M,768](f32) @ Wt^T ----------------
// 64x128 tiles + XCD-pinned linear grid (1280 blocks). BOTH operands staged via
// async gl_lds16 (the r12-proven structure): A staged as f32 (8KB, both-sides
// 16B-chunk swizzle c^(row&7)), converted f32->bf16 at fragment read; B bf16.
__global__ __launch_bounds__(256, 4) void k_gemm_gat(const float* __restrict__ A,
                                                     const unsigned short* __restrict__ Bt,
                                                     unsigned short* __restrict__ outb,
                                                     const float* __restrict__ al,
                                                     const float* __restrict__ ar,
                                                     float* __restrict__ el,
                                                     float* __restrict__ er) {
  __shared__ float Asf[64 * 32];          // 8KB f32 A-tile
  __shared__ unsigned short Bs[128 * 32]; // 8KB bf16 B-tile
  const int bid = blockIdx.x;
  const int xcd = bid & 7, t = bid >> 3;
  const int rowblk = (t >> 2) * 8 + xcd;
  if (rowblk * 64 >= NN) return;
  const int row0 = rowblk * 64;
  const int col0 = (t & 3) * 128;
  const int tid = threadIdx.x;
  const int wv = tid >> 6, lane = tid & 63;
  const int wr = (wv & 1) * 32, wc = (wv >> 1) * 64;
  const int ci = lane & 3, rsub = lane >> 2;

  f32x4 acc[2][4] = {};

  const int l15 = lane & 15;
  const int pc = (((lane >> 4) ^ ((l15 >> 1) & 3))) * 8;  // B read swizzle (bf16)
  const int q2 = (lane >> 4) * 2;                          // A chunk16 pair base
  const int s7 = l15 & 7;                                  // A read swizzle key

  // A staging per-lane source (wave-uniform dest + lane*16B is HW-defined):
  // wave wv, half i stages rows (wv*2+i)*8..+8; lane -> row += lane>>3, chunk16 = lane&7,
  // src chunk = (lane&7) ^ (lane>>3)  [since row&7 == lane>>3]
  const int al8 = lane >> 3, ac8 = lane & 7;
  const int asrcc = (ac8 ^ al8) * 4;   // f32 offset of source 16B chunk

  for (int k0 = 0; k0 < KIN; k0 += 32) {
#pragma unroll
    for (int i = 0; i < 2; i++) {
      // B: bf16 async (rows i*64 + wv*16 .. +16)
      int lrow = i * 64 + wv * 16 + rsub;
      int kc = (ci ^ ((lrow >> 1) & 3)) << 3;
      gl_lds16(Bt + (size_t)(col0 + lrow) * KIN + k0 + kc, Bs + (i * 64 + wv * 16) * 32);
      // A: f32 async (rows (wv*2+i)*8 .. +8)
      int arow0 = (wv * 2 + i) * 8;
      int ga = row0 + arow0 + al8; if (ga > NN - 1) ga = NN - 1;
      gl_lds16(A + (size_t)ga * KIN + k0 + asrcc, Asf + arow0 * 32);
    }
    __syncthreads();
    s16x8 af[2], bf4[4];
#pragma unroll
    for (int m = 0; m < 2; m++) {
      int r = wr + m * 16 + l15;
      const float* rp = Asf + r * 32;
      float4 lo = *(const float4*)(rp + ((q2 ^ s7) << 2));
      float4 hi = *(const float4*)(rp + (((q2 + 1) ^ s7) << 2));
      u4s8 u;
      u.u.x = ((unsigned)f2bf(lo.y) << 16) | f2bf(lo.x);
      u.u.y = ((unsigned)f2bf(lo.w) << 16) | f2bf(lo.z);
      u.u.z = ((unsigned)f2bf(hi.y) << 16) | f2bf(hi.x);
      u.u.w = ((unsigned)f2bf(hi.w) << 16) | f2bf(hi.z);
      af[m] = u.v;
    }
#pragma unroll
    for (int n = 0; n < 4; n++)
      bf4[n] = *(const s16x8*)(Bs + (wc + n * 16 + l15) * 32 + pc);
#pragma unroll
    for (int m = 0; m < 2; m++)
#pragma unroll
      for (int n = 0; n < 4; n++)
        acc[m][n] = __builtin_amdgcn_mfma_f32_16x16x32_bf16(af[m], bf4[n], acc[m][n], 0, 0, 0);
    __syncthreads();
  }

  const int cbase = col0 + wc + l15;
  const int rq = (lane >> 4) * 4;
  const int hd = (col0 + wc) >> 6;   // head owned by this wave
  float alc[4], arc[4];
#pragma unroll
  for (int n = 0; n < 4; n++) { alc[n] = al[cbase + n * 16]; arc[n] = ar[cbase + n * 16]; }

#pragma unroll
  for (int m = 0; m < 2; m++) {
#pragma unroll
    for (int r = 0; r < 4; r++) {
      int grow = row0 + wr + m * 16 + rq + r;
      float a = 0.f, b = 0.f;
#pragma unroll
      for (int n = 0; n < 4; n++) {
        float v = acc[m][n][r];
        a += v * alc[n];
        b += v * arc[n];
      }
      a += __shfl_xor(a, 1, 64); a += __shfl_xor(a, 2, 64);
      a += __shfl_xor(a, 4, 64); a += __shfl_xor(a, 8, 64);
      b += __shfl_xor(b, 1, 64); b += __shfl_xor(b, 2, 64);
      b += __shfl_xor(b, 4, 64); b += __shfl_xor(b, 8, 64);
      if (grow < NN) {
        unsigned short* dp = outb + (size_t)grow * NHD + cbase;
#pragma unroll
        for (int n = 0; n < 4; n++) dp[n * 16] = f2bf(acc[m][n][r]);
        if (l15 == 0) {
          el[(size_t)grow * NH + hd] = a;
          er[(size_t)grow * NH + hd] = b;
        }
      }
    }
  }
}

// ---------------- semantic GEMM with fused tanh*w2 row-reduce ----------------
__global__ __launch_bounds__(256, 2) void k_gemm_sem(const unsigned short* __restrict__ A0,
                                                     const unsigned short* __restrict__ A1,
                                                     const unsigned short* __restrict__ Bt,
                                                     const float* __restrict__ b1,
                                                     const float* __restrict__ w2,
                                                     float* __restrict__ scal) {
  __shared__ unsigned short As[128 * 32];
  __shared__ unsigned short Bs[128 * 32];
  __shared__ float rsum[2][128];
  __shared__ float pp[2][2];
  const int M = 2 * CC;
  const int tid = threadIdx.x;
  const int wv = tid >> 6, lane = tid & 63;
  const int row0 = blockIdx.x * 128;
  const int wr = (wv >> 1) * 64, wc = (wv & 1) * 64;
  const int ci = lane & 3, rsub = lane >> 2;

  f32x4 acc[4][4] = {};

  const int l15 = lane & 15;
  const int pc = (((lane >> 4) ^ ((l15 >> 1) & 3))) * 8;

  for (int k0 = 0; k0 < NHD; k0 += 32) {
#pragma unroll
    for (int i = 0; i < 2; i++) {
      int lrow = (wv * 2 + i) * 16 + rsub;
      int kc = (ci ^ ((lrow >> 1) & 3)) << 3;
      int ga = row0 + lrow; if (ga > M - 1) ga = M - 1;
      const unsigned short* Ap = (ga < CC) ? A0 + (size_t)ga * NHD
                                           : A1 + (size_t)(ga - CC) * NHD;
      gl_lds16(Ap + k0 + kc, As + (wv * 2 + i) * 512);
      int gb = lrow;  // col0 = 0, Nb = 128
      gl_lds16(Bt + (size_t)gb * NHD + k0 + kc, Bs + (wv * 2 + i) * 512);
    }
    __syncthreads();
    s16x8 af[4], bf[4];
#pragma unroll
    for (int m = 0; m < 4; m++) {
      af[m] = *(const s16x8*)(As + (wr + m * 16 + l15) * 32 + pc);
      bf[m] = *(const s16x8*)(Bs + (wc + m * 16 + l15) * 32 + pc);
    }
#pragma unroll
    for (int m = 0; m < 4; m++)
#pragma unroll
      for (int n = 0; n < 4; n++)
        acc[m][n] = __builtin_amdgcn_mfma_f32_16x16x32_bf16(af[m], bf[n], acc[m][n], 0, 0, 0);
    __syncthreads();
  }

  if (tid < 128) { rsum[0][tid] = 0.f; rsum[1][tid] = 0.f; }
  __syncthreads();
  const int cb = wc + l15;
  const int rq = (lane >> 4) * 4;
  float b1c[4], w2c[4];
#pragma unroll
  for (int n = 0; n < 4; n++) { b1c[n] = b1[cb + n * 16]; w2c[n] = w2[cb + n * 16]; }
#pragma unroll
  for (int m = 0; m < 4; m++) {
#pragma unroll
    for (int r = 0; r < 4; r++) {
      int rl = wr + m * 16 + rq + r;
      float s = 0.f;
#pragma unroll
      for (int n = 0; n < 4; n++) s += tanhf(acc[m][n][r] + b1c[n]) * w2c[n];
      s += __shfl_xor(s, 1, 64); s += __shfl_xor(s, 2, 64);
      s += __shfl_xor(s, 4, 64); s += __shfl_xor(s, 8, 64);
      if (l15 == 0 && row0 + rl < M) rsum[wv & 1][rl] = s;
    }
  }
  __syncthreads();
  if (tid < 128) {
    int grow = row0 + tid;
    float v = rsum[0][tid] + rsum[1][tid];
    float vA = (grow < CC) ? v : 0.f;
    float vB = (grow >= CC && grow < M) ? v : 0.f;
#pragma unroll
    for (int off = 32; off > 0; off >>= 1) {
      vA += __shfl_xor(vA, off, 64);
      vB += __shfl_xor(vB, off, 64);
    }
    if ((tid & 63) == 0) { pp[tid >> 6][0] = vA; pp[tid >> 6][1] = vB; }
  }
  __syncthreads();
  if (tid == 0) {
    atomicAdd(scal + 0, pp[0][0] + pp[1][0]);
    atomicAdd(scal + 1, pp[0][1] + pp[1][1]);
  }
}

// ---------------- batched CSR build (3 graphs), bucket-staged scatter ----------------
__global__ void k_hist3(const int* __restrict__ d0, const int* __restrict__ d1,
                        const int* __restrict__ d2, int* __restrict__ deg3) {
  int e = blockIdx.x * 256 + threadIdx.x;
  int g = blockIdx.y;
  const int* dst = (g == 0) ? d0 : (g == 1) ? d1 : d2;
  atomicAdd(deg3 + g * NN + dst[e], 1);
}

__global__ __launch_bounds__(1024) void k_scan3(const int* __restrict__ deg3,
                                                int* __restrict__ rowptr3,
                                                int* __restrict__ curB) {
  __shared__ int part[1024];
  const int g = blockIdx.x;
  const int* deg = deg3 + g * NN;
  int* rowptr = rowptr3 + g * (NN + 1);
  int tid = threadIdx.x;
  const int CH = 20;
  int base = tid * CH;
  int s = 0;
  for (int i = 0; i < CH; i++) { int idx = base + i; if (idx < NN) s += deg[idx]; }
  part[tid] = s;
  __syncthreads();
  for (int off = 1; off < 1024; off <<= 1) {
    int u = (tid >= off) ? part[tid - off] : 0;
    int v = part[tid];
    __syncthreads();
    part[tid] = u + v;
    __syncthreads();
  }
  int run = (tid == 0) ? 0 : part[tid - 1];
  for (int i = 0; i < CH; i++) {
    int idx = base + i;
    if (idx < NN) {
      rowptr[idx] = run;
      if ((idx & 255) == 0) curB[g * (NBKT + 1) + (idx >> 8)] = run;
      run += deg[idx];
    }
  }
  if (tid == 1023) rowptr[NN] = part[1023];
}

__global__ __launch_bounds__(1024) void k_coarse(const int* __restrict__ s0,
                                                 const int* __restrict__ s1,
                                                 const int* __restrict__ s2,
                                                 const int* __restrict__ d0,
                                                 const int* __restrict__ d1,
                                                 const int* __restrict__ d2,
                                                 int* __restrict__ curB,
                                                 unsigned* __restrict__ staging) {
  __shared__ int bcnt[NBKT];
  __shared__ int bbase[NBKT];
  int g = blockIdx.y;
  const int* src = (g == 0) ? s0 : (g == 1) ? s1 : s2;
  const int* dst = (g == 0) ? d0 : (g == 1) ? d1 : d2;
  int tid = threadIdx.x;
  if (tid < NBKT) bcnt[tid] = 0;
  __syncthreads();
  int e = blockIdx.x * 1024 + tid;
  bool val = e < NE;
  int b = 0, r = 0, sv = 0, dv = 0;
  if (val) {
    dv = dst[e]; sv = src[e];
    b = dv >> 8;
    r = atomicAdd(&bcnt[b], 1);
  }
  __syncthreads();
  if (tid < NBKT && bcnt[tid] > 0) bbase[tid] = atomicAdd(&curB[g * (NBKT + 1) + tid], bcnt[tid]);
  __syncthreads();
  if (val) staging[(size_t)g * NE + bbase[b] + r] = ((unsigned)sv << 8) | (unsigned)(dv & 255);
}

__global__ __launch_bounds__(1024) void k_fine(const int* __restrict__ rowptr3,
                                               const unsigned* __restrict__ staging,
                                               unsigned short* __restrict__ srcord3) {
  __shared__ int cur[256];
  int g = blockIdx.y, b = blockIdx.x;
  const int* rowptr = rowptr3 + g * (NN + 1);
  int n0 = b << 8;
  int tid = threadIdx.x;
  if (tid < 256) {
    int node = n0 + tid;
    cur[tid] = (node < NN) ? rowptr[node] : 0;
  }
  __syncthreads();
  int nend = n0 + 256; if (nend > NN) nend = NN;
  int start = rowptr[n0];
  int endp = rowptr[nend];
  for (int i = start + tid; i < endp; i += 1024) {
    unsigned u = staging[(size_t)g * NE + i];
    int nl = u & 255;
    int pos = atomicAdd(&cur[nl], 1);
    srcord3[(size_t)g * NE + pos] = (unsigned short)(u >> 8);
  }
}

// ---------------- FUSED softmax + gather aggregation + bias + elu (bf16 out) ----------------
// wave per node; lane = 16B slice of the 512-wide row, head = lane>>3.
__global__ __launch_bounds__(256) void k_aggf(const int* __restrict__ rowptr,
                                              const unsigned short* __restrict__ srcord,
                                              const float* __restrict__ el,
                                              const float* __restrict__ er,
                                              const unsigned short* __restrict__ hb,
                                              const float* __restrict__ bias,
                                              unsigned short* __restrict__ ob) {
  __shared__ float aS[4][64 * 8];
  __shared__ int sS[4][64];
  int wv = threadIdx.x >> 6;
  int t = (blockIdx.x * 256 + threadIdx.x) >> 6;
  int lane = threadIdx.x & 63;
  int h = lane >> 3;
  int beg = rowptr[t], end = rowptr[t + 1];

  float4 er0 = ((const float4*)(er + (size_t)t * NH))[0];
  float4 er1 = ((const float4*)(er + (size_t)t * NH))[1];
  float erow[8] = {er0.x, er0.y, er0.z, er0.w, er1.x, er1.y, er1.z, er1.w};

  float acc[8] = {0.f, 0.f, 0.f, 0.f, 0.f, 0.f, 0.f, 0.f};
  float den = 0.f;

  for (int cbeg = beg; cbeg < end; cbeg += 64) {
    int cnt = end - cbeg; if (cnt > 64) cnt = 64;
    bool valid = lane < cnt;
    int pidx = cbeg + lane; if (pidx > end - 1) pidx = end - 1;
    int s = srcord[pidx];
    if (valid) {
      sS[wv][lane] = s;
      float4 a0 = ((const float4*)(el + (size_t)s * NH))[0];
      float4 a1 = ((const float4*)(el + (size_t)s * NH))[1];
      float v[8] = {a0.x + erow[0], a0.y + erow[1], a0.z + erow[2], a0.w + erow[3],
                    a1.x + erow[4], a1.y + erow[5], a1.z + erow[6], a1.w + erow[7]};
#pragma unroll
      for (int k = 0; k < 8; k++) {
        float x = v[k];
        x = x >= 0.f ? x : 0.2f * x;
        aS[wv][lane * 8 + k] = __expf(x);
      }
    }
    const unsigned short* hbl = hb + lane * 8;
    int q = 0;
    for (; q + 3 < cnt; q += 4) {
      int s0 = sS[wv][q], s1 = sS[wv][q + 1], s2 = sS[wv][q + 2], s3 = sS[wv][q + 3];
      float w0 = aS[wv][q * 8 + h];
      float w1 = aS[wv][(q + 1) * 8 + h];
      float w2 = aS[wv][(q + 2) * 8 + h];
      float w3 = aS[wv][(q + 3) * 8 + h];
      uint4 v0 = *(const uint4*)(hbl + (size_t)s0 * NHD);
      uint4 v1 = *(const uint4*)(hbl + (size_t)s1 * NHD);
      uint4 v2 = *(const uint4*)(hbl + (size_t)s2 * NHD);
      uint4 v3 = *(const uint4*)(hbl + (size_t)s3 * NHD);
      den += (w0 + w1) + (w2 + w3);
      acc[0] += w0 * bflo(v0.x); acc[1] += w0 * bfhi(v0.x);
      acc[2] += w0 * bflo(v0.y); acc[3] += w0 * bfhi(v0.y);
      acc[4] += w0 * bflo(v0.z); acc[5] += w0 * bfhi(v0.z);
      acc[6] += w0 * bflo(v0.w); acc[7] += w0 * bfhi(v0.w);
      acc[0] += w1 * bflo(v1.x); acc[1] += w1 * bfhi(v1.x);
      acc[2] += w1 * bflo(v1.y); acc[3] += w1 * bfhi(v1.y);
      acc[4] += w1 * bflo(v1.z); acc[5] += w1 * bfhi(v1.z);
      acc[6] += w1 * bflo(v1.w); acc[7] += w1 * bfhi(v1.w);
      acc[0] += w2 * bflo(v2.x); acc[1] += w2 * bfhi(v2.x);
      acc[2] += w2 * bflo(v2.y); acc[3] += w2 * bfhi(v2.y);
      acc[4] += w2 * bflo(v2.z); acc[5] += w2 * bfhi(v2.z);
      acc[6] += w2 * bflo(v2.w); acc[7] += w2 * bfhi(v2.w);
      acc[0] += w3 * bflo(v3.x); acc[1] += w3 * bfhi(v3.x);
      acc[2] += w3 * bflo(v3.y); acc[3] += w3 * bfhi(v3.y);
      acc[4] += w3 * bflo(v3.z); acc[5] += w3 * bfhi(v3.z);
      acc[6] += w3 * bflo(v3.w); acc[7] += w3 * bfhi(v3.w);
    }
    for (; q < cnt; q++) {
      int s0 = sS[wv][q];
      float w0 = aS[wv][q * 8 + h];
      uint4 v0 = *(const uint4*)(hbl + (size_t)s0 * NHD);
      den += w0;
      acc[0] += w0 * bflo(v0.x); acc[1] += w0 * bfhi(v0.x);
      acc[2] += w0 * bflo(v0.y); acc[3] += w0 * bfhi(v0.y);
      acc[4] += w0 * bflo(v0.z); acc[5] += w0 * bfhi(v0.z);
      acc[6] += w0 * bflo(v0.w); acc[7] += w0 * bfhi(v0.w);
    }
  }

  float dn = 1.f / fmaxf(den, 1e-9f);
  float4 b0 = ((const float4*)(bias + lane * 8))[0];
  float4 b1 = ((const float4*)(bias + lane * 8))[1];
  float r[8];
  r[0] = acc[0] * dn + b0.x; r[1] = acc[1] * dn + b0.y;
  r[2] = acc[2] * dn + b0.z; r[3] = acc[3] * dn + b0.w;
  r[4] = acc[4] * dn + b1.x; r[5] = acc[5] * dn + b1.y;
  r[6] = acc[6] * dn + b1.z; r[7] = acc[7] * dn + b1.w;
#pragma unroll
  for (int j = 0; j < 8; j++) r[j] = r[j] > 0.f ? r[j] : expm1f(r[j]);
  uint4 z;
  z.x = ((unsigned)f2bf(r[1]) << 16) | f2bf(r[0]);
  z.y = ((unsigned)f2bf(r[3]) << 16) | f2bf(r[2]);
  z.z = ((unsigned)f2bf(r[5]) << 16) | f2bf(r[4]);
  z.w = ((unsigned)f2bf(r[7]) << 16) | f2bf(r[6]);
  *(uint4*)(ob + (size_t)t * NHD + lane * 8) = z;
}

// stage 1: sound(bf16) = beta0*zA(bf16) + beta1*zB(bf16)
__global__ void k_combine_s1(const float* __restrict__ scal,
                             const unsigned short* __restrict__ zA,
                             const unsigned short* __restrict__ zB,
                             unsigned short* __restrict__ outb) {
  int i = blockIdx.x * 256 + threadIdx.x;   // grid exact CC*NHD/4
  float w0 = scal[0] * (1.f / CC), w1v = scal[1] * (1.f / CC);
  float mx = fmaxf(w0, w1v);
  float e0 = expf(w0 - mx), e1 = expf(w1v - mx);
  float inv = 1.f / (e0 + e1);
  float b0 = e0 * inv, b1v = e1 * inv;
  ushort4 a = ((const ushort4*)zA)[i];
  ushort4 b = ((const ushort4*)zB)[i];
  ushort4 z;
  z.x = f2bf(b0 * bf2f(a.x) + b1v * bf2f(b.x));
  z.y = f2bf(b0 * bf2f(a.y) + b1v * bf2f(b.y));
  z.z = f2bf(b0 * bf2f(a.z) + b1v * bf2f(b.z));
  z.w = f2bf(b0 * bf2f(a.w) + b1v * bf2f(b.w));
  ((ushort4*)outb)[i] = z;
}

// ---------------- fused stage-2 combine + final head-means (bf16 inputs) ----------------
__global__ void k_comb2_means(const float* __restrict__ scal,
                              const unsigned short* __restrict__ zsound,
                              const unsigned short* __restrict__ ob0,
                              const unsigned short* __restrict__ ob1,
                              const unsigned short* __restrict__ ob2,
                              float* __restrict__ outf,
                              float* __restrict__ m1, float* __restrict__ m2,
                              float* __restrict__ m3) {
  int idx = blockIdx.x * 256 + threadIdx.x;   // grid exact NN*64
  int n = idx >> 6, d = idx & 63;
  if (n < CC) {
    float w0 = scal[0] * (1.f / CC), w1v = scal[1] * (1.f / CC);
    float mx = fmaxf(w0, w1v);
    float e0 = expf(w0 - mx), e1 = expf(w1v - mx);
    float inv = 1.f / (e0 + e1);
    float b0 = e0 * inv, b1v = e1 * inv;
    const unsigned short* zs = zsound + (size_t)n * NHD + d;
    const unsigned short* p1 = ob1 + (size_t)n * NHD + d;
    float* po = outf + (size_t)n * NHD + d;
    float v = 0.f;
#pragma unroll
    for (int h = 0; h < 8; h++) {
      float r = b0 * bf2f(zs[h * 64]) + b1v * bf2f(p1[h * 64]);
      po[h * 64] = r;
      v += r;
    }
    v *= 0.125f;
    m1[idx] = v; m2[idx] = v; m3[idx] = v;
  } else {
    const unsigned short* p0 = ob0 + (size_t)n * NHD + d;
    const unsigned short* p1 = ob1 + (size_t)n * NHD + d;
    const unsigned short* p2 = ob2 + (size_t)n * NHD + d;
    float v0 = 0.f, v1 = 0.f, v2 = 0.f;
#pragma unroll
    for (int h = 0; h < 8; h++) {
      v0 += bf2f(p0[h * 64]); v1 += bf2f(p1[h * 64]); v2 += bf2f(p2[h * 64]);
    }
    m1[idx] = v0 * 0.125f; m2[idx] = v1 * 0.125f; m3[idx] = v2 * 0.125f;
  }
}

extern "C" void kernel_launch(void* const* d_in, const int* in_sizes, int n_in,
                              void* d_out, int out_size, void* d_ws, size_t ws_size,
                              hipStream_t stream) {
  (void)in_sizes; (void)n_in; (void)out_size; (void)ws_size;

  const float* feat[3]; const int* srcp[3]; const int* dstp[3];
  const float* Wp[3]; const float* alp[3]; const float* arp[3]; const float* bp[3];
  for (int g = 0; g < 3; g++) {
    const int base = g * 8;  // dict order: feat,src,dst,char,W,al,ar,b
    feat[g] = (const float*)d_in[base + 0];
    srcp[g] = (const int*)d_in[base + 1];
    dstp[g] = (const int*)d_in[base + 2];
    Wp[g]   = (const float*)d_in[base + 4];
    alp[g]  = (const float*)d_in[base + 5];
    arp[g]  = (const float*)d_in[base + 6];
    bp[g]   = (const float*)d_in[base + 7];
  }
  const float* sw1 = (const float*)d_in[24];
  const float* sb1 = (const float*)d_in[25];
  const float* sw2 = (const float*)d_in[26];
  const float* aw1 = (const float*)d_in[27];
  const float* ab1 = (const float*)d_in[28];
  const float* aw2 = (const float*)d_in[29];

  char* wsp = (char*)d_ws;
  auto alloc = [&](size_t bytes) {
    char* p = wsp;
    wsp += (bytes + 255) & ~(size_t)255;
    return p;
  };
  // total ~103 MB
  unsigned short* ob0 = (unsigned short*)alloc((size_t)NN * NHD * 2);
  unsigned short* ob1 = (unsigned short*)alloc((size_t)NN * NHD * 2);
  unsigned short* ob2 = (unsigned short*)alloc((size_t)NN * NHD * 2);
  unsigned short* hb = (unsigned short*)alloc((size_t)NN * NHD * 2);
  unsigned short* wtb3 = (unsigned short*)alloc((size_t)3 * WTB_SZ * 2);
  unsigned short* w1tb2 = (unsigned short*)alloc((size_t)2 * W1TB_SZ * 2);
  unsigned short* sound = (unsigned short*)alloc((size_t)CC * NHD * 2);
  float* el = (float*)alloc((size_t)NN * NH * 4);
  float* er = (float*)alloc((size_t)NN * NH * 4);
  float* scal = (float*)alloc(256);
  int* deg3 = (int*)alloc((size_t)3 * NN * 4);
  int* rowptr3 = (int*)alloc((size_t)3 * (NN + 1) * 4 + 64);
  int* curB = (int*)alloc((size_t)3 * (NBKT + 1) * 4);
  unsigned* staging = (unsigned*)alloc((size_t)3 * NE * 4);
  unsigned short* srcord3 = (unsigned short*)alloc((size_t)3 * NE * 2);

  float* outf = (float*)d_out;
  float* outm1 = outf + (size_t)CC * NHD;
  float* outm2 = outm1 + (size_t)NN * ND;
  float* outm3 = outm2 + (size_t)NN * ND;

  // ---- prep: weight transposes + zero deg3/scal; bucket-staged CSR build ----
  const int PREP_T = 3 * WTB_SZ + 2 * W1TB_SZ + 3 * NN + 4;
  k_prep<<<(PREP_T + 255) / 256, 256, 0, stream>>>(Wp[0], Wp[1], Wp[2], sw1, aw1,
                                                   wtb3, w1tb2, deg3, scal);
  k_hist3<<<dim3(NE / 256, 3), 256, 0, stream>>>(dstp[0], dstp[1], dstp[2], deg3);
  k_scan3<<<3, 1024, 0, stream>>>(deg3, rowptr3, curB);
  k_coarse<<<dim3((NE + 1023) / 1024, 3), 1024, 0, stream>>>(
      srcp[0], srcp[1], srcp[2], dstp[0], dstp[1], dstp[2], curB, staging);
  k_fine<<<dim3(NBKT, 3), 1024, 0, stream>>>(rowptr3, staging, srcord3);

  // one full GAT layer for metapath g -> bf16 ob (feat read f32, async-staged + cvt at read)
  auto gat = [&](int g, unsigned short* ob) {
    k_gemm_gat<<<1280, 256, 0, stream>>>(
        feat[g], wtb3 + (size_t)g * WTB_SZ, hb, alp[g], arp[g], el, er);
    k_aggf<<<NN * 64 / 256, 256, 0, stream>>>(rowptr3 + g * (NN + 1), srcord3 + (size_t)g * NE,
                                              el, er, hb, bp[g], ob);
  };

  gat(0, ob0);
  gat(2, ob2);

  // ---- semantic stage 1: rows<CC from ob0, rows>=CC from ob2 -> sound ----
  k_gemm_sem<<<(2 * CC + 127) / 128, 256, 0, stream>>>(ob0, ob2, w1tb2, sb1, sw2, scal);
  k_combine_s1<<<CC * NHD / 4 / 256, 256, 0, stream>>>(scal, ob0, ob2, sound);

  gat(1, ob1);

  // ---- semantic stage 2: rows<CC from sound, rows>=CC from ob1 -> combine+means ----
  k_gemm_sem<<<(2 * CC + 127) / 128, 256, 0, stream>>>(sound, ob1, w1tb2 + W1TB_SZ, ab1, aw2, scal + 2);
  k_comb2_means<<<NN * 64 / 256, 256, 0, stream>>>(scal + 2, sound, ob0, ob1, ob2,
                                                   outf, outm1, outm2, outm3);
}

// Round 20
// 423.816 us; speedup vs baseline: 1.0996x; 1.0996x over previous
//
#include <hip/hip_runtime.h>
#include <math.h>

#define NN 20000
#define NE 320000
#define CC 10000
#define KIN 768
#define NH 8
#define ND 64
#define NHD 512
#define NSA 128
#define NBKT 79                 // buckets of 256 nodes: 79*256 = 20224 >= NN

#define WTB_SZ (NHD * KIN)      // 393216 per graph
#define W1TB_SZ (NSA * NHD)     // 65536 per stage
#define APAD 72                 // A LDS row stride (bf16): 64 + 8 pad -> 144B, 16B-aligned

typedef __attribute__((ext_vector_type(4))) float f32x4;
typedef __attribute__((ext_vector_type(8))) short s16x8;

__device__ __forceinline__ unsigned short f2bf(float f) {
  unsigned u = __float_as_uint(f);
  u += 0x7fffu + ((u >> 16) & 1u);
  return (unsigned short)(u >> 16);
}
__device__ __forceinline__ float bf2f(unsigned short s) {
  return __uint_as_float(((unsigned)s) << 16);
}
__device__ __forceinline__ float bflo(unsigned u) { return __uint_as_float(u << 16); }
__device__ __forceinline__ float bfhi(unsigned u) { return __uint_as_float(u & 0xffff0000u); }

__device__ __forceinline__ void gl_lds16(const void* g, void* l) {
  __builtin_amdgcn_global_load_lds(
      (const __attribute__((address_space(1))) unsigned int*)g,
      (__attribute__((address_space(3))) unsigned int*)l, 16, 0, 0);
}

// ---------------- prep: all weight transposes + zero deg3 + zero scal ----------------
__global__ void k_prep(const float* __restrict__ W0, const float* __restrict__ W1,
                       const float* __restrict__ W2, const float* __restrict__ sw1,
                       const float* __restrict__ aw1, unsigned short* __restrict__ wtb3,
                       unsigned short* __restrict__ w1tb2, int* __restrict__ deg3,
                       float* __restrict__ scal) {
  int i = blockIdx.x * 256 + threadIdx.x;
  if (i < 3 * WTB_SZ) {
    int g = i / WTB_SZ;
    int j = i - g * WTB_SZ;
    int n = j / KIN, k = j - n * KIN;
    const float* W = (g == 0) ? W0 : (g == 1) ? W1 : W2;
    wtb3[i] = f2bf(W[(size_t)k * NHD + n]);
    return;
  }
  i -= 3 * WTB_SZ;
  if (i < 2 * W1TB_SZ) {
    int p = i / W1TB_SZ;
    int j = i - p * W1TB_SZ;
    int n = j / NHD, k = j - n * NHD;
    const float* W = p ? aw1 : sw1;
    w1tb2[p * W1TB_SZ + n * NHD + k] = f2bf(W[(size_t)k * NSA + n]);
    return;
  }
  i -= 2 * W1TB_SZ;
  if (i < 3 * NN) { deg3[i] = 0; return; }
  i -= 3 * NN;
  if (i < 4) scal[i] = 0.f;
}

// ---------------- GAT GEMM: hb[M,512](bf16) = A[M,768](f32, cast inline) @ Wt^T ----------------
// 64x128 tiles + XCD-pinned linear grid (1280 blocks). BK=64: half the barriers
// (12 iters), 16 MFMA/wave per barrier. A: reg-cast f32->bf16 into padded LDS
// [64][72] (no swizzle, 2-way banks both sides). B: async gl_lds16 into [128][64]
// with both-sides chunk^(row&7) involution.
__global__ __launch_bounds__(256, 4) void k_gemm_gat(const float* __restrict__ A,
                                                     const unsigned short* __restrict__ Bt,
                                                     unsigned short* __restrict__ outb,
                                                     const float* __restrict__ al,
                                                     const float* __restrict__ ar,
                                                     float* __restrict__ el,
                                                     float* __restrict__ er) {
  __shared__ unsigned short As[64 * APAD];   // 9.2 KB
  __shared__ unsigned short Bs[128 * 64];    // 16 KB
  const int bid = blockIdx.x;
  const int xcd = bid & 7, t = bid >> 3;
  const int rowblk = (t >> 2) * 8 + xcd;
  if (rowblk * 64 >= NN) return;
  const int row0 = rowblk * 64;
  const int col0 = (t & 3) * 128;
  const int tid = threadIdx.x;
  const int wv = tid >> 6, lane = tid & 63;
  const int wr = (wv & 1) * 32, wc = (wv >> 1) * 64;

  f32x4 acc[2][4] = {};

  const int l15 = lane & 15;
  const int q = lane >> 4;              // 0..3 (k-chunk within 32-k subtile)

  // A staging: thread (arow = tid>>2, ci = tid&3) stages chunks {ci, ci+4} (no swizzle)
  const int arow = tid >> 2, ci = tid & 3;
  int aga = row0 + arow; if (aga > NN - 1) aga = NN - 1;
  const float* ap = A + (size_t)aga * KIN;

  // B staging per-lane source (both-sides involution chunk^(row&7)):
  const int bl8 = lane >> 3, bc8 = lane & 7;
  const int bsrcc = (bc8 ^ bl8) * 8;    // bf16 offset of source chunk

  for (int k0 = 0; k0 < KIN; k0 += 64) {
    // B: 4 async issues per wave (rows (wv*4+j)*8 .. +8)
#pragma unroll
    for (int j = 0; j < 4; j++) {
      int rb0 = (wv * 4 + j) * 8;
      int grow = col0 + rb0 + bl8;     // always < 512
      gl_lds16(Bt + (size_t)grow * KIN + k0 + bsrcc, Bs + rb0 * 64);
    }
    // A: 2 chunks per thread, f32 -> bf16 pack, padded LDS
#pragma unroll
    for (int sc = 0; sc < 2; sc++) {
      int s = ci + sc * 4;
      const float* sp = ap + k0 + s * 8;
      float4 f0 = ((const float4*)sp)[0];
      float4 f1 = ((const float4*)sp)[1];
      uint4 pk;
      pk.x = ((unsigned)f2bf(f0.y) << 16) | f2bf(f0.x);
      pk.y = ((unsigned)f2bf(f0.w) << 16) | f2bf(f0.z);
      pk.z = ((unsigned)f2bf(f1.y) << 16) | f2bf(f1.x);
      pk.w = ((unsigned)f2bf(f1.w) << 16) | f2bf(f1.z);
      *(uint4*)(As + arow * APAD + s * 8) = pk;
    }
    __syncthreads();
#pragma unroll
    for (int kk = 0; kk < 2; kk++) {
      s16x8 af[2], bf4[4];
#pragma unroll
      for (int m = 0; m < 2; m++) {
        int r = wr + m * 16 + l15;
        af[m] = *(const s16x8*)(As + r * APAD + (kk * 4 + q) * 8);
      }
#pragma unroll
      for (int n = 0; n < 4; n++) {
        int rB = wc + n * 16 + l15;
        int slot = (kk * 4 + q) ^ (rB & 7);
        bf4[n] = *(const s16x8*)(Bs + rB * 64 + slot * 8);
      }
#pragma unroll
      for (int m = 0; m < 2; m++)
#pragma unroll
        for (int n = 0; n < 4; n++)
          acc[m][n] = __builtin_amdgcn_mfma_f32_16x16x32_bf16(af[m], bf4[n], acc[m][n], 0, 0, 0);
    }
    __syncthreads();
  }

  const int cbase = col0 + wc + l15;
  const int rq = (lane >> 4) * 4;
  const int hd = (col0 + wc) >> 6;   // head owned by this wave
  float alc[4], arc[4];
#pragma unroll
  for (int n = 0; n < 4; n++) { alc[n] = al[cbase + n * 16]; arc[n] = ar[cbase + n * 16]; }

#pragma unroll
  for (int m = 0; m < 2; m++) {
#pragma unroll
    for (int r = 0; r < 4; r++) {
      int grow = row0 + wr + m * 16 + rq + r;
      float a = 0.f, b = 0.f;
#pragma unroll
      for (int n = 0; n < 4; n++) {
        float v = acc[m][n][r];
        a += v * alc[n];
        b += v * arc[n];
      }
      a += __shfl_xor(a, 1, 64); a += __shfl_xor(a, 2, 64);
      a += __shfl_xor(a, 4, 64); a += __shfl_xor(a, 8, 64);
      b += __shfl_xor(b, 1, 64); b += __shfl_xor(b, 2, 64);
      b += __shfl_xor(b, 4, 64); b += __shfl_xor(b, 8, 64);
      if (grow < NN) {
        unsigned short* dp = outb + (size_t)grow * NHD + cbase;
#pragma unroll
        for (int n = 0; n < 4; n++) dp[n * 16] = f2bf(acc[m][n][r]);
        if (l15 == 0) {
          el[(size_t)grow * NH + hd] = a;
          er[(size_t)grow * NH + hd] = b;
        }
      }
    }
  }
}

// ---------------- semantic GEMM with fused tanh*w2 row-reduce ----------------
__global__ __launch_bounds__(256, 2) void k_gemm_sem(const unsigned short* __restrict__ A0,
                                                     const unsigned short* __restrict__ A1,
                                                     const unsigned short* __restrict__ Bt,
                                                     const float* __restrict__ b1,
                                                     const float* __restrict__ w2,
                                                     float* __restrict__ scal) {
  __shared__ unsigned short As[128 * 32];
  __shared__ unsigned short Bs[128 * 32];
  __shared__ float rsum[2][128];
  __shared__ float pp[2][2];
  const int M = 2 * CC;
  const int tid = threadIdx.x;
  const int wv = tid >> 6, lane = tid & 63;
  const int row0 = blockIdx.x * 128;
  const int wr = (wv >> 1) * 64, wc = (wv & 1) * 64;
  const int ci = lane & 3, rsub = lane >> 2;

  f32x4 acc[4][4] = {};

  const int l15 = lane & 15;
  const int pc = (((lane >> 4) ^ ((l15 >> 1) & 3))) * 8;

  for (int k0 = 0; k0 < NHD; k0 += 32) {
#pragma unroll
    for (int i = 0; i < 2; i++) {
      int lrow = (wv * 2 + i) * 16 + rsub;
      int kc = (ci ^ ((lrow >> 1) & 3)) << 3;
      int ga = row0 + lrow; if (ga > M - 1) ga = M - 1;
      const unsigned short* Ap = (ga < CC) ? A0 + (size_t)ga * NHD
                                           : A1 + (size_t)(ga - CC) * NHD;
      gl_lds16(Ap + k0 + kc, As + (wv * 2 + i) * 512);
      int gb = lrow;  // col0 = 0, Nb = 128
      gl_lds16(Bt + (size_t)gb * NHD + k0 + kc, Bs + (wv * 2 + i) * 512);
    }
    __syncthreads();
    s16x8 af[4], bf[4];
#pragma unroll
    for (int m = 0; m < 4; m++) {
      af[m] = *(const s16x8*)(As + (wr + m * 16 + l15) * 32 + pc);
      bf[m] = *(const s16x8*)(Bs + (wc + m * 16 + l15) * 32 + pc);
    }
#pragma unroll
    for (int m = 0; m < 4; m++)
#pragma unroll
      for (int n = 0; n < 4; n++)
        acc[m][n] = __builtin_amdgcn_mfma_f32_16x16x32_bf16(af[m], bf[n], acc[m][n], 0, 0, 0);
    __syncthreads();
  }

  if (tid < 128) { rsum[0][tid] = 0.f; rsum[1][tid] = 0.f; }
  __syncthreads();
  const int cb = wc + l15;
  const int rq = (lane >> 4) * 4;
  float b1c[4], w2c[4];
#pragma unroll
  for (int n = 0; n < 4; n++) { b1c[n] = b1[cb + n * 16]; w2c[n] = w2[cb + n * 16]; }
#pragma unroll
  for (int m = 0; m < 4; m++) {
#pragma unroll
    for (int r = 0; r < 4; r++) {
      int rl = wr + m * 16 + rq + r;
      float s = 0.f;
#pragma unroll
      for (int n = 0; n < 4; n++) s += tanhf(acc[m][n][r] + b1c[n]) * w2c[n];
      s += __shfl_xor(s, 1, 64); s += __shfl_xor(s, 2, 64);
      s += __shfl_xor(s, 4, 64); s += __shfl_xor(s, 8, 64);
      if (l15 == 0 && row0 + rl < M) rsum[wv & 1][rl] = s;
    }
  }
  __syncthreads();
  if (tid < 128) {
    int grow = row0 + tid;
    float v = rsum[0][tid] + rsum[1][tid];
    float vA = (grow < CC) ? v : 0.f;
    float vB = (grow >= CC && grow < M) ? v : 0.f;
#pragma unroll
    for (int off = 32; off > 0; off >>= 1) {
      vA += __shfl_xor(vA, off, 64);
      vB += __shfl_xor(vB, off, 64);
    }
    if ((tid & 63) == 0) { pp[tid >> 6][0] = vA; pp[tid >> 6][1] = vB; }
  }
  __syncthreads();
  if (tid == 0) {
    atomicAdd(scal + 0, pp[0][0] + pp[1][0]);
    atomicAdd(scal + 1, pp[0][1] + pp[1][1]);
  }
}

// ---------------- batched CSR build (3 graphs), bucket-staged scatter ----------------
__global__ void k_hist3(const int* __restrict__ d0, const int* __restrict__ d1,
                        const int* __restrict__ d2, int* __restrict__ deg3) {
  int e = blockIdx.x * 256 + threadIdx.x;
  int g = blockIdx.y;
  const int* dst = (g == 0) ? d0 : (g == 1) ? d1 : d2;
  atomicAdd(deg3 + g * NN + dst[e], 1);
}

__global__ __launch_bounds__(1024) void k_scan3(const int* __restrict__ deg3,
                                                int* __restrict__ rowptr3,
                                                int* __restrict__ curB) {
  __shared__ int part[1024];
  const int g = blockIdx.x;
  const int* deg = deg3 + g * NN;
  int* rowptr = rowptr3 + g * (NN + 1);
  int tid = threadIdx.x;
  const int CH = 20;
  int base = tid * CH;
  int s = 0;
  for (int i = 0; i < CH; i++) { int idx = base + i; if (idx < NN) s += deg[idx]; }
  part[tid] = s;
  __syncthreads();
  for (int off = 1; off < 1024; off <<= 1) {
    int u = (tid >= off) ? part[tid - off] : 0;
    int v = part[tid];
    __syncthreads();
    part[tid] = u + v;
    __syncthreads();
  }
  int run = (tid == 0) ? 0 : part[tid - 1];
  for (int i = 0; i < CH; i++) {
    int idx = base + i;
    if (idx < NN) {
      rowptr[idx] = run;
      if ((idx & 255) == 0) curB[g * (NBKT + 1) + (idx >> 8)] = run;
      run += deg[idx];
    }
  }
  if (tid == 1023) rowptr[NN] = part[1023];
}

__global__ __launch_bounds__(1024) void k_coarse(const int* __restrict__ s0,
                                                 const int* __restrict__ s1,
                                                 const int* __restrict__ s2,
                                                 const int* __restrict__ d0,
                                                 const int* __restrict__ d1,
                                                 const int* __restrict__ d2,
                                                 int* __restrict__ curB,
                                                 unsigned* __restrict__ staging) {
  __shared__ int bcnt[NBKT];
  __shared__ int bbase[NBKT];
  int g = blockIdx.y;
  const int* src = (g == 0) ? s0 : (g == 1) ? s1 : s2;
  const int* dst = (g == 0) ? d0 : (g == 1) ? d1 : d2;
  int tid = threadIdx.x;
  if (tid < NBKT) bcnt[tid] = 0;
  __syncthreads();
  int e = blockIdx.x * 1024 + tid;
  bool val = e < NE;
  int b = 0, r = 0, sv = 0, dv = 0;
  if (val) {
    dv = dst[e]; sv = src[e];
    b = dv >> 8;
    r = atomicAdd(&bcnt[b], 1);
  }
  __syncthreads();
  if (tid < NBKT && bcnt[tid] > 0) bbase[tid] = atomicAdd(&curB[g * (NBKT + 1) + tid], bcnt[tid]);
  __syncthreads();
  if (val) staging[(size_t)g * NE + bbase[b] + r] = ((unsigned)sv << 8) | (unsigned)(dv & 255);
}

__global__ __launch_bounds__(1024) void k_fine(const int* __restrict__ rowptr3,
                                               const unsigned* __restrict__ staging,
                                               unsigned short* __restrict__ srcord3) {
  __shared__ int cur[256];
  int g = blockIdx.y, b = blockIdx.x;
  const int* rowptr = rowptr3 + g * (NN + 1);
  int n0 = b << 8;
  int tid = threadIdx.x;
  if (tid < 256) {
    int node = n0 + tid;
    cur[tid] = (node < NN) ? rowptr[node] : 0;
  }
  __syncthreads();
  int nend = n0 + 256; if (nend > NN) nend = NN;
  int start = rowptr[n0];
  int endp = rowptr[nend];
  for (int i = start + tid; i < endp; i += 1024) {
    unsigned u = staging[(size_t)g * NE + i];
    int nl = u & 255;
    int pos = atomicAdd(&cur[nl], 1);
    srcord3[(size_t)g * NE + pos] = (unsigned short)(u >> 8);
  }
}

// ---------------- FUSED softmax + gather aggregation + bias + elu (bf16 out) ----------------
// wave per node; lane = 16B slice of the 512-wide row, head = lane>>3.
__global__ __launch_bounds__(256) void k_aggf(const int* __restrict__ rowptr,
                                              const unsigned short* __restrict__ srcord,
                                              const float* __restrict__ el,
                                              const float* __restrict__ er,
                                              const unsigned short* __restrict__ hb,
                                              const float* __restrict__ bias,
                                              unsigned short* __restrict__ ob) {
  __shared__ float aS[4][64 * 8];
  __shared__ int sS[4][64];
  int wv = threadIdx.x >> 6;
  int t = (blockIdx.x * 256 + threadIdx.x) >> 6;
  int lane = threadIdx.x & 63;
  int h = lane >> 3;
  int beg = rowptr[t], end = rowptr[t + 1];

  float4 er0 = ((const float4*)(er + (size_t)t * NH))[0];
  float4 er1 = ((const float4*)(er + (size_t)t * NH))[1];
  float erow[8] = {er0.x, er0.y, er0.z, er0.w, er1.x, er1.y, er1.z, er1.w};

  float acc[8] = {0.f, 0.f, 0.f, 0.f, 0.f, 0.f, 0.f, 0.f};
  float den = 0.f;

  for (int cbeg = beg; cbeg < end; cbeg += 64) {
    int cnt = end - cbeg; if (cnt > 64) cnt = 64;
    bool valid = lane < cnt;
    int pidx = cbeg + lane; if (pidx > end - 1) pidx = end - 1;
    int s = srcord[pidx];
    if (valid) {
      sS[wv][lane] = s;
      float4 a0 = ((const float4*)(el + (size_t)s * NH))[0];
      float4 a1 = ((const float4*)(el + (size_t)s * NH))[1];
      float v[8] = {a0.x + erow[0], a0.y + erow[1], a0.z + erow[2], a0.w + erow[3],
                    a1.x + erow[4], a1.y + erow[5], a1.z + erow[6], a1.w + erow[7]};
#pragma unroll
      for (int k = 0; k < 8; k++) {
        float x = v[k];
        x = x >= 0.f ? x : 0.2f * x;
        aS[wv][lane * 8 + k] = __expf(x);
      }
    }
    const unsigned short* hbl = hb + lane * 8;
    int q = 0;
    for (; q + 3 < cnt; q += 4) {
      int s0 = sS[wv][q], s1 = sS[wv][q + 1], s2 = sS[wv][q + 2], s3 = sS[wv][q + 3];
      float w0 = aS[wv][q * 8 + h];
      float w1 = aS[wv][(q + 1) * 8 + h];
      float w2 = aS[wv][(q + 2) * 8 + h];
      float w3 = aS[wv][(q + 3) * 8 + h];
      uint4 v0 = *(const uint4*)(hbl + (size_t)s0 * NHD);
      uint4 v1 = *(const uint4*)(hbl + (size_t)s1 * NHD);
      uint4 v2 = *(const uint4*)(hbl + (size_t)s2 * NHD);
      uint4 v3 = *(const uint4*)(hbl + (size_t)s3 * NHD);
      den += (w0 + w1) + (w2 + w3);
      acc[0] += w0 * bflo(v0.x); acc[1] += w0 * bfhi(v0.x);
      acc[2] += w0 * bflo(v0.y); acc[3] += w0 * bfhi(v0.y);
      acc[4] += w0 * bflo(v0.z); acc[5] += w0 * bfhi(v0.z);
      acc[6] += w0 * bflo(v0.w); acc[7] += w0 * bfhi(v0.w);
      acc[0] += w1 * bflo(v1.x); acc[1] += w1 * bfhi(v1.x);
      acc[2] += w1 * bflo(v1.y); acc[3] += w1 * bfhi(v1.y);
      acc[4] += w1 * bflo(v1.z); acc[5] += w1 * bfhi(v1.z);
      acc[6] += w1 * bflo(v1.w); acc[7] += w1 * bfhi(v1.w);
      acc[0] += w2 * bflo(v2.x); acc[1] += w2 * bfhi(v2.x);
      acc[2] += w2 * bflo(v2.y); acc[3] += w2 * bfhi(v2.y);
      acc[4] += w2 * bflo(v2.z); acc[5] += w2 * bfhi(v2.z);
      acc[6] += w2 * bflo(v2.w); acc[7] += w2 * bfhi(v2.w);
      acc[0] += w3 * bflo(v3.x); acc[1] += w3 * bfhi(v3.x);
      acc[2] += w3 * bflo(v3.y); acc[3] += w3 * bfhi(v3.y);
      acc[4] += w3 * bflo(v3.z); acc[5] += w3 * bfhi(v3.z);
      acc[6] += w3 * bflo(v3.w); acc[7] += w3 * bfhi(v3.w);
    }
    for (; q < cnt; q++) {
      int s0 = sS[wv][q];
      float w0 = aS[wv][q * 8 + h];
      uint4 v0 = *(const uint4*)(hbl + (size_t)s0 * NHD);
      den += w0;
      acc[0] += w0 * bflo(v0.x); acc[1] += w0 * bfhi(v0.x);
      acc[2] += w0 * bflo(v0.y); acc[3] += w0 * bfhi(v0.y);
      acc[4] += w0 * bflo(v0.z); acc[5] += w0 * bfhi(v0.z);
      acc[6] += w0 * bflo(v0.w); acc[7] += w0 * bfhi(v0.w);
    }
  }

  float dn = 1.f / fmaxf(den, 1e-9f);
  float4 b0 = ((const float4*)(bias + lane * 8))[0];
  float4 b1 = ((const float4*)(bias + lane * 8))[1];
  float r[8];
  r[0] = acc[0] * dn + b0.x; r[1] = acc[1] * dn + b0.y;
  r[2] = acc[2] * dn + b0.z; r[3] = acc[3] * dn + b0.w;
  r[4] = acc[4] * dn + b1.x; r[5] = acc[5] * dn + b1.y;
  r[6] = acc[6] * dn + b1.z; r[7] = acc[7] * dn + b1.w;
#pragma unroll
  for (int j = 0; j < 8; j++) r[j] = r[j] > 0.f ? r[j] : expm1f(r[j]);
  uint4 z;
  z.x = ((unsigned)f2bf(r[1]) << 16) | f2bf(r[0]);
  z.y = ((unsigned)f2bf(r[3]) << 16) | f2bf(r[2]);
  z.z = ((unsigned)f2bf(r[5]) << 16) | f2bf(r[4]);
  z.w = ((unsigned)f2bf(r[7]) << 16) | f2bf(r[6]);
  *(uint4*)(ob + (size_t)t * NHD + lane * 8) = z;
}

// stage 1: sound(bf16) = beta0*zA(bf16) + beta1*zB(bf16)
__global__ void k_combine_s1(const float* __restrict__ scal,
                             const unsigned short* __restrict__ zA,
                             const unsigned short* __restrict__ zB,
                             unsigned short* __restrict__ outb) {
  int i = blockIdx.x * 256 + threadIdx.x;   // grid exact CC*NHD/4
  float w0 = scal[0] * (1.f / CC), w1v = scal[1] * (1.f / CC);
  float mx = fmaxf(w0, w1v);
  float e0 = expf(w0 - mx), e1 = expf(w1v - mx);
  float inv = 1.f / (e0 + e1);
  float b0 = e0 * inv, b1v = e1 * inv;
  ushort4 a = ((const ushort4*)zA)[i];
  ushort4 b = ((const ushort4*)zB)[i];
  ushort4 z;
  z.x = f2bf(b0 * bf2f(a.x) + b1v * bf2f(b.x));
  z.y = f2bf(b0 * bf2f(a.y) + b1v * bf2f(b.y));
  z.z = f2bf(b0 * bf2f(a.z) + b1v * bf2f(b.z));
  z.w = f2bf(b0 * bf2f(a.w) + b1v * bf2f(b.w));
  ((ushort4*)outb)[i] = z;
}

// ---------------- fused stage-2 combine + final head-means (bf16 inputs) ----------------
__global__ void k_comb2_means(const float* __restrict__ scal,
                              const unsigned short* __restrict__ zsound,
                              const unsigned short* __restrict__ ob0,
                              const unsigned short* __restrict__ ob1,
                              const unsigned short* __restrict__ ob2,
                              float* __restrict__ outf,
                              float* __restrict__ m1, float* __restrict__ m2,
                              float* __restrict__ m3) {
  int idx = blockIdx.x * 256 + threadIdx.x;   // grid exact NN*64
  int n = idx >> 6, d = idx & 63;
  if (n < CC) {
    float w0 = scal[0] * (1.f / CC), w1v = scal[1] * (1.f / CC);
    float mx = fmaxf(w0, w1v);
    float e0 = expf(w0 - mx), e1 = expf(w1v - mx);
    float inv = 1.f / (e0 + e1);
    float b0 = e0 * inv, b1v = e1 * inv;
    const unsigned short* zs = zsound + (size_t)n * NHD + d;
    const unsigned short* p1 = ob1 + (size_t)n * NHD + d;
    float* po = outf + (size_t)n * NHD + d;
    float v = 0.f;
#pragma unroll
    for (int h = 0; h < 8; h++) {
      float r = b0 * bf2f(zs[h * 64]) + b1v * bf2f(p1[h * 64]);
      po[h * 64] = r;
      v += r;
    }
    v *= 0.125f;
    m1[idx] = v; m2[idx] = v; m3[idx] = v;
  } else {
    const unsigned short* p0 = ob0 + (size_t)n * NHD + d;
    const unsigned short* p1 = ob1 + (size_t)n * NHD + d;
    const unsigned short* p2 = ob2 + (size_t)n * NHD + d;
    float v0 = 0.f, v1 = 0.f, v2 = 0.f;
#pragma unroll
    for (int h = 0; h < 8; h++) {
      v0 += bf2f(p0[h * 64]); v1 += bf2f(p1[h * 64]); v2 += bf2f(p2[h * 64]);
    }
    m1[idx] = v0 * 0.125f; m2[idx] = v1 * 0.125f; m3[idx] = v2 * 0.125f;
  }
}

extern "C" void kernel_launch(void* const* d_in, const int* in_sizes, int n_in,
                              void* d_out, int out_size, void* d_ws, size_t ws_size,
                              hipStream_t stream) {
  (void)in_sizes; (void)n_in; (void)out_size; (void)ws_size;

  const float* feat[3]; const int* srcp[3]; const int* dstp[3];
  const float* Wp[3]; const float* alp[3]; const float* arp[3]; const float* bp[3];
  for (int g = 0; g < 3; g++) {
    const int base = g * 8;  // dict order: feat,src,dst,char,W,al,ar,b
    feat[g] = (const float*)d_in[base + 0];
    srcp[g] = (const int*)d_in[base + 1];
    dstp[g] = (const int*)d_in[base + 2];
    Wp[g]   = (const float*)d_in[base + 4];
    alp[g]  = (const float*)d_in[base + 5];
    arp[g]  = (const float*)d_in[base + 6];
    bp[g]   = (const float*)d_in[base + 7];
  }
  const float* sw1 = (const float*)d_in[24];
  const float* sb1 = (const float*)d_in[25];
  const float* sw2 = (const float*)d_in[26];
  const float* aw1 = (const float*)d_in[27];
  const float* ab1 = (const float*)d_in[28];
  const float* aw2 = (const float*)d_in[29];

  char* wsp = (char*)d_ws;
  auto alloc = [&](size_t bytes) {
    char* p = wsp;
    wsp += (bytes + 255) & ~(size_t)255;
    return p;
  };
  // total ~103 MB
  unsigned short* ob0 = (unsigned short*)alloc((size_t)NN * NHD * 2);
  unsigned short* ob1 = (unsigned short*)alloc((size_t)NN * NHD * 2);
  unsigned short* ob2 = (unsigned short*)alloc((size_t)NN * NHD * 2);
  unsigned short* hb = (unsigned short*)alloc((size_t)NN * NHD * 2);
  unsigned short* wtb3 = (unsigned short*)alloc((size_t)3 * WTB_SZ * 2);
  unsigned short* w1tb2 = (unsigned short*)alloc((size_t)2 * W1TB_SZ * 2);
  unsigned short* sound = (unsigned short*)alloc((size_t)CC * NHD * 2);
  float* el = (float*)alloc((size_t)NN * NH * 4);
  float* er = (float*)alloc((size_t)NN * NH * 4);
  float* scal = (float*)alloc(256);
  int* deg3 = (int*)alloc((size_t)3 * NN * 4);
  int* rowptr3 = (int*)alloc((size_t)3 * (NN + 1) * 4 + 64);
  int* curB = (int*)alloc((size_t)3 * (NBKT + 1) * 4);
  unsigned* staging = (unsigned*)alloc((size_t)3 * NE * 4);
  unsigned short* srcord3 = (unsigned short*)alloc((size_t)3 * NE * 2);

  float* outf = (float*)d_out;
  float* outm1 = outf + (size_t)CC * NHD;
  float* outm2 = outm1 + (size_t)NN * ND;
  float* outm3 = outm2 + (size_t)NN * ND;

  // ---- prep: weight transposes + zero deg3/scal; bucket-staged CSR build ----
  const int PREP_T = 3 * WTB_SZ + 2 * W1TB_SZ + 3 * NN + 4;
  k_prep<<<(PREP_T + 255) / 256, 256, 0, stream>>>(Wp[0], Wp[1], Wp[2], sw1, aw1,
                                                   wtb3, w1tb2, deg3, scal);
  k_hist3<<<dim3(NE / 256, 3), 256, 0, stream>>>(dstp[0], dstp[1], dstp[2], deg3);
  k_scan3<<<3, 1024, 0, stream>>>(deg3, rowptr3, curB);
  k_coarse<<<dim3((NE + 1023) / 1024, 3), 1024, 0, stream>>>(
      srcp[0], srcp[1], srcp[2], dstp[0], dstp[1], dstp[2], curB, staging);
  k_fine<<<dim3(NBKT, 3), 1024, 0, stream>>>(rowptr3, staging, srcord3);

  // one full GAT layer for metapath g -> bf16 ob (feat read f32, cast inline, BK=64)
  auto gat = [&](int g, unsigned short* ob) {
    k_gemm_gat<<<1280, 256, 0, stream>>>(
        feat[g], wtb3 + (size_t)g * WTB_SZ, hb, alp[g], arp[g], el, er);
    k_aggf<<<NN * 64 / 256, 256, 0, stream>>>(rowptr3 + g * (NN + 1), srcord3 + (size_t)g * NE,
                                              el, er, hb, bp[g], ob);
  };

  gat(0, ob0);
  gat(2, ob2);

  // ---- semantic stage 1: rows<CC from ob0, rows>=CC from ob2 -> sound ----
  k_gemm_sem<<<(2 * CC + 127) / 128, 256, 0, stream>>>(ob0, ob2, w1tb2, sb1, sw2, scal);
  k_combine_s1<<<CC * NHD / 4 / 256, 256, 0, stream>>>(scal, ob0, ob2, sound);

  gat(1, ob1);

  // ---- semantic stage 2: rows<CC from sound, rows>=CC from ob1 -> combine+means ----
  k_gemm_sem<<<(2 * CC + 127) / 128, 256, 0, stream>>>(sound, ob1, w1tb2 + W1TB_SZ, ab1, aw2, scal + 2);
  k_comb2_means<<<NN * 64 / 256, 256, 0, stream>>>(scal + 2, sound, ob0, ob1, ob2,
                                                   outf, outm1, outm2, outm3);
}

// Round 21
// 423.261 us; speedup vs baseline: 1.1010x; 1.0013x over previous
//
#include <hip/hip_runtime.h>
#include <math.h>

#define NN 20000
#define NE 320000
#define CC 10000
#define KIN 768
#define NH 8
#define ND 64
#define NHD 512
#define NSA 128
#define NBKT 79                 // buckets of 256 nodes: 79*256 = 20224 >= NN

#define WTB_SZ (NHD * KIN)      // 393216 per graph
#define W1TB_SZ (NSA * NHD)     // 65536 per stage
#define APAD 136                // A LDS row stride (bf16): 128 + 8 pad -> 272B, 16B-aligned

typedef __attribute__((ext_vector_type(4))) float f32x4;
typedef __attribute__((ext_vector_type(8))) short s16x8;

__device__ __forceinline__ unsigned short f2bf(float f) {
  unsigned u = __float_as_uint(f);
  u += 0x7fffu + ((u >> 16) & 1u);
  return (unsigned short)(u >> 16);
}
__device__ __forceinline__ float bf2f(unsigned short s) {
  return __uint_as_float(((unsigned)s) << 16);
}
__device__ __forceinline__ float bflo(unsigned u) { return __uint_as_float(u << 16); }
__device__ __forceinline__ float bfhi(unsigned u) { return __uint_as_float(u & 0xffff0000u); }

__device__ __forceinline__ void gl_lds16(const void* g, void* l) {
  __builtin_amdgcn_global_load_lds(
      (const __attribute__((address_space(1))) unsigned int*)g,
      (__attribute__((address_space(3))) unsigned int*)l, 16, 0, 0);
}

// ---------------- prep: all weight transposes + zero deg3 + zero scal ----------------
__global__ void k_prep(const float* __restrict__ W0, const float* __restrict__ W1,
                       const float* __restrict__ W2, const float* __restrict__ sw1,
                       const float* __restrict__ aw1, unsigned short* __restrict__ wtb3,
                       unsigned short* __restrict__ w1tb2, int* __restrict__ deg3,
                       float* __restrict__ scal) {
  int i = blockIdx.x * 256 + threadIdx.x;
  if (i < 3 * WTB_SZ) {
    int g = i / WTB_SZ;
    int j = i - g * WTB_SZ;
    int n = j / KIN, k = j - n * KIN;
    const float* W = (g == 0) ? W0 : (g == 1) ? W1 : W2;
    wtb3[i] = f2bf(W[(size_t)k * NHD + n]);
    return;
  }
  i -= 3 * WTB_SZ;
  if (i < 2 * W1TB_SZ) {
    int p = i / W1TB_SZ;
    int j = i - p * W1TB_SZ;
    int n = j / NHD, k = j - n * NHD;
    const float* W = p ? aw1 : sw1;
    w1tb2[p * W1TB_SZ + n * NHD + k] = f2bf(W[(size_t)k * NSA + n]);
    return;
  }
  i -= 2 * W1TB_SZ;
  if (i < 3 * NN) { deg3[i] = 0; return; }
  i -= 3 * NN;
  if (i < 4) scal[i] = 0.f;
}

// ---------------- GAT GEMM: hb[M,512](bf16) = A[M,768](f32, cast inline) @ Wt^T ----------------
// 64x128 tiles + XCD-pinned linear grid (1280 blocks). BK=128: 6 iterations,
// 32 MFMA/wave per barrier (r20 proved barrier-drain is the bottleneck:
// BK 32->64 gave 64->51us). A: reg-cast f32->bf16 into padded LDS [64][136].
// B: async gl_lds16 into [128][128] with both-sides chunk^(row&15) involution.
// LDS 49.4KB -> 3 blocks/CU.
__global__ __launch_bounds__(256, 2) void k_gemm_gat(const float* __restrict__ A,
                                                     const unsigned short* __restrict__ Bt,
                                                     unsigned short* __restrict__ outb,
                                                     const float* __restrict__ al,
                                                     const float* __restrict__ ar,
                                                     float* __restrict__ el,
                                                     float* __restrict__ er) {
  __shared__ unsigned short As[64 * APAD];    // 17.4 KB
  __shared__ unsigned short Bs[128 * 128];    // 32 KB
  const int bid = blockIdx.x;
  const int xcd = bid & 7, t = bid >> 3;
  const int rowblk = (t >> 2) * 8 + xcd;
  if (rowblk * 64 >= NN) return;
  const int row0 = rowblk * 64;
  const int col0 = (t & 3) * 128;
  const int tid = threadIdx.x;
  const int wv = tid >> 6, lane = tid & 63;
  const int wr = (wv & 1) * 32, wc = (wv >> 1) * 64;

  f32x4 acc[2][4] = {};

  const int l15 = lane & 15;
  const int q = lane >> 4;              // 0..3 (k-chunk within 32-k subtile)

  // A staging: thread (arow = tid>>2, ci = tid&3) stages chunks {ci, ci+4, ci+8, ci+12}
  const int arow = tid >> 2, ci = tid & 3;
  int aga = row0 + arow; if (aga > NN - 1) aga = NN - 1;
  const float* ap = A + (size_t)aga * KIN;

  // B staging: per wave 8 issues; issue j covers rows rb0=(wv*8+j)*4 .. +4.
  // lane -> (inrow = lane>>4, ch = lane&15); source chunk = ch ^ (grow&15)
  // where grow&15 = (j&3)*4 + inrow  (both-sides involution).
  const int binrow = lane >> 4, bch = lane & 15;

  for (int k0 = 0; k0 < KIN; k0 += 128) {
    // B: 8 async issues per wave
#pragma unroll
    for (int j = 0; j < 8; j++) {
      int rb0 = (wv * 8 + j) * 4;
      int grow = col0 + rb0 + binrow;     // always < 512
      int srcch = bch ^ ((j & 3) * 4 + binrow);
      gl_lds16(Bt + (size_t)grow * KIN + k0 + srcch * 8, Bs + rb0 * 128);
    }
    // A: 4 chunks per thread, f32 -> bf16 pack, padded LDS (no swizzle)
#pragma unroll
    for (int sc = 0; sc < 4; sc++) {
      int s = ci + sc * 4;
      const float* sp = ap + k0 + s * 8;
      float4 f0 = ((const float4*)sp)[0];
      float4 f1 = ((const float4*)sp)[1];
      uint4 pk;
      pk.x = ((unsigned)f2bf(f0.y) << 16) | f2bf(f0.x);
      pk.y = ((unsigned)f2bf(f0.w) << 16) | f2bf(f0.z);
      pk.z = ((unsigned)f2bf(f1.y) << 16) | f2bf(f1.x);
      pk.w = ((unsigned)f2bf(f1.w) << 16) | f2bf(f1.z);
      *(uint4*)(As + arow * APAD + s * 8) = pk;
    }
    __syncthreads();
#pragma unroll
    for (int kk = 0; kk < 4; kk++) {
      s16x8 af[2], bf4[4];
#pragma unroll
      for (int m = 0; m < 2; m++) {
        int r = wr + m * 16 + l15;
        af[m] = *(const s16x8*)(As + r * APAD + (kk * 4 + q) * 8);
      }
#pragma unroll
      for (int n = 0; n < 4; n++) {
        int rB = wc + n * 16 + l15;
        int slot = (kk * 4 + q) ^ l15;      // rB&15 == l15
        bf4[n] = *(const s16x8*)(Bs + rB * 128 + slot * 8);
      }
#pragma unroll
      for (int m = 0; m < 2; m++)
#pragma unroll
        for (int n = 0; n < 4; n++)
          acc[m][n] = __builtin_amdgcn_mfma_f32_16x16x32_bf16(af[m], bf4[n], acc[m][n], 0, 0, 0);
    }
    __syncthreads();
  }

  const int cbase = col0 + wc + l15;
  const int rq = (lane >> 4) * 4;
  const int hd = (col0 + wc) >> 6;   // head owned by this wave
  float alc[4], arc[4];
#pragma unroll
  for (int n = 0; n < 4; n++) { alc[n] = al[cbase + n * 16]; arc[n] = ar[cbase + n * 16]; }

#pragma unroll
  for (int m = 0; m < 2; m++) {
#pragma unroll
    for (int r = 0; r < 4; r++) {
      int grow = row0 + wr + m * 16 + rq + r;
      float a = 0.f, b = 0.f;
#pragma unroll
      for (int n = 0; n < 4; n++) {
        float v = acc[m][n][r];
        a += v * alc[n];
        b += v * arc[n];
      }
      a += __shfl_xor(a, 1, 64); a += __shfl_xor(a, 2, 64);
      a += __shfl_xor(a, 4, 64); a += __shfl_xor(a, 8, 64);
      b += __shfl_xor(b, 1, 64); b += __shfl_xor(b, 2, 64);
      b += __shfl_xor(b, 4, 64); b += __shfl_xor(b, 8, 64);
      if (grow < NN) {
        unsigned short* dp = outb + (size_t)grow * NHD + cbase;
#pragma unroll
        for (int n = 0; n < 4; n++) dp[n * 16] = f2bf(acc[m][n][r]);
        if (l15 == 0) {
          el[(size_t)grow * NH + hd] = a;
          er[(size_t)grow * NH + hd] = b;
        }
      }
    }
  }
}

// ---------------- semantic GEMM with fused tanh*w2 row-reduce ----------------
__global__ __launch_bounds__(256, 2) void k_gemm_sem(const unsigned short* __restrict__ A0,
                                                     const unsigned short* __restrict__ A1,
                                                     const unsigned short* __restrict__ Bt,
                                                     const float* __restrict__ b1,
                                                     const float* __restrict__ w2,
                                                     float* __restrict__ scal) {
  __shared__ unsigned short As[128 * 32];
  __shared__ unsigned short Bs[128 * 32];
  __shared__ float rsum[2][128];
  __shared__ float pp[2][2];
  const int M = 2 * CC;
  const int tid = threadIdx.x;
  const int wv = tid >> 6, lane = tid & 63;
  const int row0 = blockIdx.x * 128;
  const int wr = (wv >> 1) * 64, wc = (wv & 1) * 64;
  const int ci = lane & 3, rsub = lane >> 2;

  f32x4 acc[4][4] = {};

  const int l15 = lane & 15;
  const int pc = (((lane >> 4) ^ ((l15 >> 1) & 3))) * 8;

  for (int k0 = 0; k0 < NHD; k0 += 32) {
#pragma unroll
    for (int i = 0; i < 2; i++) {
      int lrow = (wv * 2 + i) * 16 + rsub;
      int kc = (ci ^ ((lrow >> 1) & 3)) << 3;
      int ga = row0 + lrow; if (ga > M - 1) ga = M - 1;
      const unsigned short* Ap = (ga < CC) ? A0 + (size_t)ga * NHD
                                           : A1 + (size_t)(ga - CC) * NHD;
      gl_lds16(Ap + k0 + kc, As + (wv * 2 + i) * 512);
      int gb = lrow;  // col0 = 0, Nb = 128
      gl_lds16(Bt + (size_t)gb * NHD + k0 + kc, Bs + (wv * 2 + i) * 512);
    }
    __syncthreads();
    s16x8 af[4], bf[4];
#pragma unroll
    for (int m = 0; m < 4; m++) {
      af[m] = *(const s16x8*)(As + (wr + m * 16 + l15) * 32 + pc);
      bf[m] = *(const s16x8*)(Bs + (wc + m * 16 + l15) * 32 + pc);
    }
#pragma unroll
    for (int m = 0; m < 4; m++)
#pragma unroll
      for (int n = 0; n < 4; n++)
        acc[m][n] = __builtin_amdgcn_mfma_f32_16x16x32_bf16(af[m], bf[n], acc[m][n], 0, 0, 0);
    __syncthreads();
  }

  if (tid < 128) { rsum[0][tid] = 0.f; rsum[1][tid] = 0.f; }
  __syncthreads();
  const int cb = wc + l15;
  const int rq = (lane >> 4) * 4;
  float b1c[4], w2c[4];
#pragma unroll
  for (int n = 0; n < 4; n++) { b1c[n] = b1[cb + n * 16]; w2c[n] = w2[cb + n * 16]; }
#pragma unroll
  for (int m = 0; m < 4; m++) {
#pragma unroll
    for (int r = 0; r < 4; r++) {
      int rl = wr + m * 16 + rq + r;
      float s = 0.f;
#pragma unroll
      for (int n = 0; n < 4; n++) s += tanhf(acc[m][n][r] + b1c[n]) * w2c[n];
      s += __shfl_xor(s, 1, 64); s += __shfl_xor(s, 2, 64);
      s += __shfl_xor(s, 4, 64); s += __shfl_xor(s, 8, 64);
      if (l15 == 0 && row0 + rl < M) rsum[wv & 1][rl] = s;
    }
  }
  __syncthreads();
  if (tid < 128) {
    int grow = row0 + tid;
    float v = rsum[0][tid] + rsum[1][tid];
    float vA = (grow < CC) ? v : 0.f;
    float vB = (grow >= CC && grow < M) ? v : 0.f;
#pragma unroll
    for (int off = 32; off > 0; off >>= 1) {
      vA += __shfl_xor(vA, off, 64);
      vB += __shfl_xor(vB, off, 64);
    }
    if ((tid & 63) == 0) { pp[tid >> 6][0] = vA; pp[tid >> 6][1] = vB; }
  }
  __syncthreads();
  if (tid == 0) {
    atomicAdd(scal + 0, pp[0][0] + pp[1][0]);
    atomicAdd(scal + 1, pp[0][1] + pp[1][1]);
  }
}

// ---------------- batched CSR build (3 graphs), bucket-staged scatter ----------------
__global__ void k_hist3(const int* __restrict__ d0, const int* __restrict__ d1,
                        const int* __restrict__ d2, int* __restrict__ deg3) {
  int e = blockIdx.x * 256 + threadIdx.x;
  int g = blockIdx.y;
  const int* dst = (g == 0) ? d0 : (g == 1) ? d1 : d2;
  atomicAdd(deg3 + g * NN + dst[e], 1);
}

__global__ __launch_bounds__(1024) void k_scan3(const int* __restrict__ deg3,
                                                int* __restrict__ rowptr3,
                                                int* __restrict__ curB) {
  __shared__ int part[1024];
  const int g = blockIdx.x;
  const int* deg = deg3 + g * NN;
  int* rowptr = rowptr3 + g * (NN + 1);
  int tid = threadIdx.x;
  const int CH = 20;
  int base = tid * CH;
  int s = 0;
  for (int i = 0; i < CH; i++) { int idx = base + i; if (idx < NN) s += deg[idx]; }
  part[tid] = s;
  __syncthreads();
  for (int off = 1; off < 1024; off <<= 1) {
    int u = (tid >= off) ? part[tid - off] : 0;
    int v = part[tid];
    __syncthreads();
    part[tid] = u + v;
    __syncthreads();
  }
  int run = (tid == 0) ? 0 : part[tid - 1];
  for (int i = 0; i < CH; i++) {
    int idx = base + i;
    if (idx < NN) {
      rowptr[idx] = run;
      if ((idx & 255) == 0) curB[g * (NBKT + 1) + (idx >> 8)] = run;
      run += deg[idx];
    }
  }
  if (tid == 1023) rowptr[NN] = part[1023];
}

__global__ __launch_bounds__(1024) void k_coarse(const int* __restrict__ s0,
                                                 const int* __restrict__ s1,
                                                 const int* __restrict__ s2,
                                                 const int* __restrict__ d0,
                                                 const int* __restrict__ d1,
                                                 const int* __restrict__ d2,
                                                 int* __restrict__ curB,
                                                 unsigned* __restrict__ staging) {
  __shared__ int bcnt[NBKT];
  __shared__ int bbase[NBKT];
  int g = blockIdx.y;
  const int* src = (g == 0) ? s0 : (g == 1) ? s1 : s2;
  const int* dst = (g == 0) ? d0 : (g == 1) ? d1 : d2;
  int tid = threadIdx.x;
  if (tid < NBKT) bcnt[tid] = 0;
  __syncthreads();
  int e = blockIdx.x * 1024 + tid;
  bool val = e < NE;
  int b = 0, r = 0, sv = 0, dv = 0;
  if (val) {
    dv = dst[e]; sv = src[e];
    b = dv >> 8;
    r = atomicAdd(&bcnt[b], 1);
  }
  __syncthreads();
  if (tid < NBKT && bcnt[tid] > 0) bbase[tid] = atomicAdd(&curB[g * (NBKT + 1) + tid], bcnt[tid]);
  __syncthreads();
  if (val) staging[(size_t)g * NE + bbase[b] + r] = ((unsigned)sv << 8) | (unsigned)(dv & 255);
}

__global__ __launch_bounds__(1024) void k_fine(const int* __restrict__ rowptr3,
                                               const unsigned* __restrict__ staging,
                                               unsigned short* __restrict__ srcord3) {
  __shared__ int cur[256];
  int g = blockIdx.y, b = blockIdx.x;
  const int* rowptr = rowptr3 + g * (NN + 1);
  int n0 = b << 8;
  int tid = threadIdx.x;
  if (tid < 256) {
    int node = n0 + tid;
    cur[tid] = (node < NN) ? rowptr[node] : 0;
  }
  __syncthreads();
  int nend = n0 + 256; if (nend > NN) nend = NN;
  int start = rowptr[n0];
  int endp = rowptr[nend];
  for (int i = start + tid; i < endp; i += 1024) {
    unsigned u = staging[(size_t)g * NE + i];
    int nl = u & 255;
    int pos = atomicAdd(&cur[nl], 1);
    srcord3[(size_t)g * NE + pos] = (unsigned short)(u >> 8);
  }
}

// ---------------- FUSED softmax + gather aggregation + bias + elu (bf16 out) ----------------
// wave per node; lane = 16B slice of the 512-wide row, head = lane>>3.
__global__ __launch_bounds__(256) void k_aggf(const int* __restrict__ rowptr,
                                              const unsigned short* __restrict__ srcord,
                                              const float* __restrict__ el,
                                              const float* __restrict__ er,
                                              const unsigned short* __restrict__ hb,
                                              const float* __restrict__ bias,
                                              unsigned short* __restrict__ ob) {
  __shared__ float aS[4][64 * 8];
  __shared__ int sS[4][64];
  int wv = threadIdx.x >> 6;
  int t = (blockIdx.x * 256 + threadIdx.x) >> 6;
  int lane = threadIdx.x & 63;
  int h = lane >> 3;
  int beg = rowptr[t], end = rowptr[t + 1];

  float4 er0 = ((const float4*)(er + (size_t)t * NH))[0];
  float4 er1 = ((const float4*)(er + (size_t)t * NH))[1];
  float erow[8] = {er0.x, er0.y, er0.z, er0.w, er1.x, er1.y, er1.z, er1.w};

  float acc[8] = {0.f, 0.f, 0.f, 0.f, 0.f, 0.f, 0.f, 0.f};
  float den = 0.f;

  for (int cbeg = beg; cbeg < end; cbeg += 64) {
    int cnt = end - cbeg; if (cnt > 64) cnt = 64;
    bool valid = lane < cnt;
    int pidx = cbeg + lane; if (pidx > end - 1) pidx = end - 1;
    int s = srcord[pidx];
    if (valid) {
      sS[wv][lane] = s;
      float4 a0 = ((const float4*)(el + (size_t)s * NH))[0];
      float4 a1 = ((const float4*)(el + (size_t)s * NH))[1];
      float v[8] = {a0.x + erow[0], a0.y + erow[1], a0.z + erow[2], a0.w + erow[3],
                    a1.x + erow[4], a1.y + erow[5], a1.z + erow[6], a1.w + erow[7]};
#pragma unroll
      for (int k = 0; k < 8; k++) {
        float x = v[k];
        x = x >= 0.f ? x : 0.2f * x;
        aS[wv][lane * 8 + k] = __expf(x);
      }
    }
    const unsigned short* hbl = hb + lane * 8;
    int q = 0;
    for (; q + 3 < cnt; q += 4) {
      int s0 = sS[wv][q], s1 = sS[wv][q + 1], s2 = sS[wv][q + 2], s3 = sS[wv][q + 3];
      float w0 = aS[wv][q * 8 + h];
      float w1 = aS[wv][(q + 1) * 8 + h];
      float w2 = aS[wv][(q + 2) * 8 + h];
      float w3 = aS[wv][(q + 3) * 8 + h];
      uint4 v0 = *(const uint4*)(hbl + (size_t)s0 * NHD);
      uint4 v1 = *(const uint4*)(hbl + (size_t)s1 * NHD);
      uint4 v2 = *(const uint4*)(hbl + (size_t)s2 * NHD);
      uint4 v3 = *(const uint4*)(hbl + (size_t)s3 * NHD);
      den += (w0 + w1) + (w2 + w3);
      acc[0] += w0 * bflo(v0.x); acc[1] += w0 * bfhi(v0.x);
      acc[2] += w0 * bflo(v0.y); acc[3] += w0 * bfhi(v0.y);
      acc[4] += w0 * bflo(v0.z); acc[5] += w0 * bfhi(v0.z);
      acc[6] += w0 * bflo(v0.w); acc[7] += w0 * bfhi(v0.w);
      acc[0] += w1 * bflo(v1.x); acc[1] += w1 * bfhi(v1.x);
      acc[2] += w1 * bflo(v1.y); acc[3] += w1 * bfhi(v1.y);
      acc[4] += w1 * bflo(v1.z); acc[5] += w1 * bfhi(v1.z);
      acc[6] += w1 * bflo(v1.w); acc[7] += w1 * bfhi(v1.w);
      acc[0] += w2 * bflo(v2.x); acc[1] += w2 * bfhi(v2.x);
      acc[2] += w2 * bflo(v2.y); acc[3] += w2 * bfhi(v2.y);
      acc[4] += w2 * bflo(v2.z); acc[5] += w2 * bfhi(v2.z);
      acc[6] += w2 * bflo(v2.w); acc[7] += w2 * bfhi(v2.w);
      acc[0] += w3 * bflo(v3.x); acc[1] += w3 * bfhi(v3.x);
      acc[2] += w3 * bflo(v3.y); acc[3] += w3 * bfhi(v3.y);
      acc[4] += w3 * bflo(v3.z); acc[5] += w3 * bfhi(v3.z);
      acc[6] += w3 * bflo(v3.w); acc[7] += w3 * bfhi(v3.w);
    }
    for (; q < cnt; q++) {
      int s0 = sS[wv][q];
      float w0 = aS[wv][q * 8 + h];
      uint4 v0 = *(const uint4*)(hbl + (size_t)s0 * NHD);
      den += w0;
      acc[0] += w0 * bflo(v0.x); acc[1] += w0 * bfhi(v0.x);
      acc[2] += w0 * bflo(v0.y); acc[3] += w0 * bfhi(v0.y);
      acc[4] += w0 * bflo(v0.z); acc[5] += w0 * bfhi(v0.z);
      acc[6] += w0 * bflo(v0.w); acc[7] += w0 * bfhi(v0.w);
    }
  }

  float dn = 1.f / fmaxf(den, 1e-9f);
  float4 b0 = ((const float4*)(bias + lane * 8))[0];
  float4 b1 = ((const float4*)(bias + lane * 8))[1];
  float r[8];
  r[0] = acc[0] * dn + b0.x; r[1] = acc[1] * dn + b0.y;
  r[2] = acc[2] * dn + b0.z; r[3] = acc[3] * dn + b0.w;
  r[4] = acc[4] * dn + b1.x; r[5] = acc[5] * dn + b1.y;
  r[6] = acc[6] * dn + b1.z; r[7] = acc[7] * dn + b1.w;
#pragma unroll
  for (int j = 0; j < 8; j++) r[j] = r[j] > 0.f ? r[j] : expm1f(r[j]);
  uint4 z;
  z.x = ((unsigned)f2bf(r[1]) << 16) | f2bf(r[0]);
  z.y = ((unsigned)f2bf(r[3]) << 16) | f2bf(r[2]);
  z.z = ((unsigned)f2bf(r[5]) << 16) | f2bf(r[4]);
  z.w = ((unsigned)f2bf(r[7]) << 16) | f2bf(r[6]);
  *(uint4*)(ob + (size_t)t * NHD + lane * 8) = z;
}

// stage 1: sound(bf16) = beta0*zA(bf16) + beta1*zB(bf16)
__global__ void k_combine_s1(const float* __restrict__ scal,
                             const unsigned short* __restrict__ zA,
                             const unsigned short* __restrict__ zB,
                             unsigned short* __restrict__ outb) {
  int i = blockIdx.x * 256 + threadIdx.x;   // grid exact CC*NHD/4
  float w0 = scal[0] * (1.f / CC), w1v = scal[1] * (1.f / CC);
  float mx = fmaxf(w0, w1v);
  float e0 = expf(w0 - mx), e1 = expf(w1v - mx);
  float inv = 1.f / (e0 + e1);
  float b0 = e0 * inv, b1v = e1 * inv;
  ushort4 a = ((const ushort4*)zA)[i];
  ushort4 b = ((const ushort4*)zB)[i];
  ushort4 z;
  z.x = f2bf(b0 * bf2f(a.x) + b1v * bf2f(b.x));
  z.y = f2bf(b0 * bf2f(a.y) + b1v * bf2f(b.y));
  z.z = f2bf(b0 * bf2f(a.z) + b1v * bf2f(b.z));
  z.w = f2bf(b0 * bf2f(a.w) + b1v * bf2f(b.w));
  ((ushort4*)outb)[i] = z;
}

// ---------------- fused stage-2 combine + final head-means (bf16 inputs) ----------------
__global__ void k_comb2_means(const float* __restrict__ scal,
                              const unsigned short* __restrict__ zsound,
                              const unsigned short* __restrict__ ob0,
                              const unsigned short* __restrict__ ob1,
                              const unsigned short* __restrict__ ob2,
                              float* __restrict__ outf,
                              float* __restrict__ m1, float* __restrict__ m2,
                              float* __restrict__ m3) {
  int idx = blockIdx.x * 256 + threadIdx.x;   // grid exact NN*64
  int n = idx >> 6, d = idx & 63;
  if (n < CC) {
    float w0 = scal[0] * (1.f / CC), w1v = scal[1] * (1.f / CC);
    float mx = fmaxf(w0, w1v);
    float e0 = expf(w0 - mx), e1 = expf(w1v - mx);
    float inv = 1.f / (e0 + e1);
    float b0 = e0 * inv, b1v = e1 * inv;
    const unsigned short* zs = zsound + (size_t)n * NHD + d;
    const unsigned short* p1 = ob1 + (size_t)n * NHD + d;
    float* po = outf + (size_t)n * NHD + d;
    float v = 0.f;
#pragma unroll
    for (int h = 0; h < 8; h++) {
      float r = b0 * bf2f(zs[h * 64]) + b1v * bf2f(p1[h * 64]);
      po[h * 64] = r;
      v += r;
    }
    v *= 0.125f;
    m1[idx] = v; m2[idx] = v; m3[idx] = v;
  } else {
    const unsigned short* p0 = ob0 + (size_t)n * NHD + d;
    const unsigned short* p1 = ob1 + (size_t)n * NHD + d;
    const unsigned short* p2 = ob2 + (size_t)n * NHD + d;
    float v0 = 0.f, v1 = 0.f, v2 = 0.f;
#pragma unroll
    for (int h = 0; h < 8; h++) {
      v0 += bf2f(p0[h * 64]); v1 += bf2f(p1[h * 64]); v2 += bf2f(p2[h * 64]);
    }
    m1[idx] = v0 * 0.125f; m2[idx] = v1 * 0.125f; m3[idx] = v2 * 0.125f;
  }
}

extern "C" void kernel_launch(void* const* d_in, const int* in_sizes, int n_in,
                              void* d_out, int out_size, void* d_ws, size_t ws_size,
                              hipStream_t stream) {
  (void)in_sizes; (void)n_in; (void)out_size; (void)ws_size;

  const float* feat[3]; const int* srcp[3]; const int* dstp[3];
  const float* Wp[3]; const float* alp[3]; const float* arp[3]; const float* bp[3];
  for (int g = 0; g < 3; g++) {
    const int base = g * 8;  // dict order: feat,src,dst,char,W,al,ar,b
    feat[g] = (const float*)d_in[base + 0];
    srcp[g] = (const int*)d_in[base + 1];
    dstp[g] = (const int*)d_in[base + 2];
    Wp[g]   = (const float*)d_in[base + 4];
    alp[g]  = (const float*)d_in[base + 5];
    arp[g]  = (const float*)d_in[base + 6];
    bp[g]   = (const float*)d_in[base + 7];
  }
  const float* sw1 = (const float*)d_in[24];
  const float* sb1 = (const float*)d_in[25];
  const float* sw2 = (const float*)d_in[26];
  const float* aw1 = (const float*)d_in[27];
  const float* ab1 = (const float*)d_in[28];
  const float* aw2 = (const float*)d_in[29];

  char* wsp = (char*)d_ws;
  auto alloc = [&](size_t bytes) {
    char* p = wsp;
    wsp += (bytes + 255) & ~(size_t)255;
    return p;
  };
  // total ~103 MB
  unsigned short* ob0 = (unsigned short*)alloc((size_t)NN * NHD * 2);
  unsigned short* ob1 = (unsigned short*)alloc((size_t)NN * NHD * 2);
  unsigned short* ob2 = (unsigned short*)alloc((size_t)NN * NHD * 2);
  unsigned short* hb = (unsigned short*)alloc((size_t)NN * NHD * 2);
  unsigned short* wtb3 = (unsigned short*)alloc((size_t)3 * WTB_SZ * 2);
  unsigned short* w1tb2 = (unsigned short*)alloc((size_t)2 * W1TB_SZ * 2);
  unsigned short* sound = (unsigned short*)alloc((size_t)CC * NHD * 2);
  float* el = (float*)alloc((size_t)NN * NH * 4);
  float* er = (float*)alloc((size_t)NN * NH * 4);
  float* scal = (float*)alloc(256);
  int* deg3 = (int*)alloc((size_t)3 * NN * 4);
  int* rowptr3 = (int*)alloc((size_t)3 * (NN + 1) * 4 + 64);
  int* curB = (int*)alloc((size_t)3 * (NBKT + 1) * 4);
  unsigned* staging = (unsigned*)alloc((size_t)3 * NE * 4);
  unsigned short* srcord3 = (unsigned short*)alloc((size_t)3 * NE * 2);

  float* outf = (float*)d_out;
  float* outm1 = outf + (size_t)CC * NHD;
  float* outm2 = outm1 + (size_t)NN * ND;
  float* outm3 = outm2 + (size_t)NN * ND;

  // ---- prep: weight transposes + zero deg3/scal; bucket-staged CSR build ----
  const int PREP_T = 3 * WTB_SZ + 2 * W1TB_SZ + 3 * NN + 4;
  k_prep<<<(PREP_T + 255) / 256, 256, 0, stream>>>(Wp[0], Wp[1], Wp[2], sw1, aw1,
                                                   wtb3, w1tb2, deg3, scal);
  k_hist3<<<dim3(NE / 256, 3), 256, 0, stream>>>(dstp[0], dstp[1], dstp[2], deg3);
  k_scan3<<<3, 1024, 0, stream>>>(deg3, rowptr3, curB);
  k_coarse<<<dim3((NE + 1023) / 1024, 3), 1024, 0, stream>>>(
      srcp[0], srcp[1], srcp[2], dstp[0], dstp[1], dstp[2], curB, staging);
  k_fine<<<dim3(NBKT, 3), 1024, 0, stream>>>(rowptr3, staging, srcord3);

  // one full GAT layer for metapath g -> bf16 ob (feat read f32, cast inline, BK=128)
  auto gat = [&](int g, unsigned short* ob) {
    k_gemm_gat<<<1280, 256, 0, stream>>>(
        feat[g], wtb3 + (size_t)g * WTB_SZ, hb, alp[g], arp[g], el, er);
    k_aggf<<<NN * 64 / 256, 256, 0, stream>>>(rowptr3 + g * (NN + 1), srcord3 + (size_t)g * NE,
                                              el, er, hb, bp[g], ob);
  };

  gat(0, ob0);
  gat(2, ob2);

  // ---- semantic stage 1: rows<CC from ob0, rows>=CC from ob2 -> sound ----
  k_gemm_sem<<<(2 * CC + 127) / 128, 256, 0, stream>>>(ob0, ob2, w1tb2, sb1, sw2, scal);
  k_combine_s1<<<CC * NHD / 4 / 256, 256, 0, stream>>>(scal, ob0, ob2, sound);

  gat(1, ob1);

  // ---- semantic stage 2: rows<CC from sound, rows>=CC from ob1 -> combine+means ----
  k_gemm_sem<<<(2 * CC + 127) / 128, 256, 0, stream>>>(sound, ob1, w1tb2 + W1TB_SZ, ab1, aw2, scal + 2);
  k_comb2_means<<<NN * 64 / 256, 256, 0, stream>>>(scal + 2, sound, ob0, ob1, ob2,
                                                   outf, outm1, outm2, outm3);
}

// Round 22
// 410.953 us; speedup vs baseline: 1.1340x; 1.0299x over previous
//
#include <hip/hip_runtime.h>
#include <math.h>

#define NN 20000
#define NE 320000
#define CC 10000
#define KIN 768
#define NH 8
#define ND 64
#define NHD 512
#define NSA 128
#define NBKT 79                 // buckets of 256 nodes: 79*256 = 20224 >= NN

#define WTB_SZ (NHD * KIN)      // 393216 per graph
#define W1TB_SZ (NSA * NHD)     // 65536 per stage
#define APAD 136                // A LDS row stride (bf16): 128 + 8 pad -> 272B, 16B-aligned
#define GB 1280                 // gemm blocks per graph

typedef __attribute__((ext_vector_type(4))) float f32x4;
typedef __attribute__((ext_vector_type(8))) short s16x8;

__device__ __forceinline__ unsigned short f2bf(float f) {
  unsigned u = __float_as_uint(f);
  u += 0x7fffu + ((u >> 16) & 1u);
  return (unsigned short)(u >> 16);
}
__device__ __forceinline__ float bf2f(unsigned short s) {
  return __uint_as_float(((unsigned)s) << 16);
}
__device__ __forceinline__ float bflo(unsigned u) { return __uint_as_float(u << 16); }
__device__ __forceinline__ float bfhi(unsigned u) { return __uint_as_float(u & 0xffff0000u); }

__device__ __forceinline__ void gl_lds16(const void* g, void* l) {
  __builtin_amdgcn_global_load_lds(
      (const __attribute__((address_space(1))) unsigned int*)g,
      (__attribute__((address_space(3))) unsigned int*)l, 16, 0, 0);
}

// ---------------- prep: all weight transposes + zero deg3 + zero scal ----------------
__global__ void k_prep(const float* __restrict__ W0, const float* __restrict__ W1,
                       const float* __restrict__ W2, const float* __restrict__ sw1,
                       const float* __restrict__ aw1, unsigned short* __restrict__ wtb3,
                       unsigned short* __restrict__ w1tb2, int* __restrict__ deg3,
                       float* __restrict__ scal) {
  int i = blockIdx.x * 256 + threadIdx.x;
  if (i < 3 * WTB_SZ) {
    int g = i / WTB_SZ;
    int j = i - g * WTB_SZ;
    int n = j / KIN, k = j - n * KIN;
    const float* W = (g == 0) ? W0 : (g == 1) ? W1 : W2;
    wtb3[i] = f2bf(W[(size_t)k * NHD + n]);
    return;
  }
  i -= 3 * WTB_SZ;
  if (i < 2 * W1TB_SZ) {
    int p = i / W1TB_SZ;
    int j = i - p * W1TB_SZ;
    int n = j / NHD, k = j - n * NHD;
    const float* W = p ? aw1 : sw1;
    w1tb2[p * W1TB_SZ + n * NHD + k] = f2bf(W[(size_t)k * NSA + n]);
    return;
  }
  i -= 2 * W1TB_SZ;
  if (i < 3 * NN) { deg3[i] = 0; return; }
  i -= 3 * NN;
  if (i < 4) scal[i] = 0.f;
}

// ---------------- GAT GEMM, 3 graphs batched ----------------
// Per graph: 64x128 tiles + XCD-pinned decode (GB=1280 divisible by 8 so bid&7
// keeps the pin), BK=128 (6 barrier-pairs, r20/21-proven best). A: reg-cast
// f32->bf16 into padded LDS [64][136]; B: async gl_lds16 into [128][128] with
// both-sides chunk^(row&15) involution. Fused el/er epilogue.
__global__ __launch_bounds__(256, 2) void k_gemm_gat3(
    const float* __restrict__ f0, const float* __restrict__ f1, const float* __restrict__ f2,
    const unsigned short* __restrict__ wtb3, unsigned short* __restrict__ hb3,
    const float* __restrict__ al0, const float* __restrict__ al1, const float* __restrict__ al2,
    const float* __restrict__ ar0, const float* __restrict__ ar1, const float* __restrict__ ar2,
    float* __restrict__ el3, float* __restrict__ er3) {
  __shared__ unsigned short As[64 * APAD];    // 17.4 KB
  __shared__ unsigned short Bs[128 * 128];    // 32 KB
  const int bidg = blockIdx.x;
  const int g = bidg / GB;
  const int bid = bidg - g * GB;
  const int xcd = bidg & 7, t = bid >> 3;     // bid&7 == bidg&7 (GB % 8 == 0)
  const int rowblk = (t >> 2) * 8 + xcd;
  if (rowblk * 64 >= NN) return;
  const float* A = (g == 0) ? f0 : (g == 1) ? f1 : f2;
  const float* al = (g == 0) ? al0 : (g == 1) ? al1 : al2;
  const float* ar = (g == 0) ? ar0 : (g == 1) ? ar1 : ar2;
  const unsigned short* Bt = wtb3 + (size_t)g * WTB_SZ;
  unsigned short* outb = hb3 + (size_t)g * NN * NHD;
  float* el = el3 + (size_t)g * NN * NH;
  float* er = er3 + (size_t)g * NN * NH;

  const int row0 = rowblk * 64;
  const int col0 = (t & 3) * 128;
  const int tid = threadIdx.x;
  const int wv = tid >> 6, lane = tid & 63;
  const int wr = (wv & 1) * 32, wc = (wv >> 1) * 64;

  f32x4 acc[2][4] = {};

  const int l15 = lane & 15;
  const int q = lane >> 4;              // 0..3 (k-chunk within 32-k subtile)

  // A staging: thread (arow = tid>>2, ci = tid&3) stages chunks {ci, ci+4, ci+8, ci+12}
  const int arow = tid >> 2, ci = tid & 3;
  int aga = row0 + arow; if (aga > NN - 1) aga = NN - 1;
  const float* ap = A + (size_t)aga * KIN;

  // B staging: per wave 8 issues; issue j covers rows rb0=(wv*8+j)*4 .. +4.
  const int binrow = lane >> 4, bch = lane & 15;

  for (int k0 = 0; k0 < KIN; k0 += 128) {
#pragma unroll
    for (int j = 0; j < 8; j++) {
      int rb0 = (wv * 8 + j) * 4;
      int grow = col0 + rb0 + binrow;     // always < 512
      int srcch = bch ^ ((j & 3) * 4 + binrow);
      gl_lds16(Bt + (size_t)grow * KIN + k0 + srcch * 8, Bs + rb0 * 128);
    }
#pragma unroll
    for (int sc = 0; sc < 4; sc++) {
      int s = ci + sc * 4;
      const float* sp = ap + k0 + s * 8;
      float4 fa = ((const float4*)sp)[0];
      float4 fb = ((const float4*)sp)[1];
      uint4 pk;
      pk.x = ((unsigned)f2bf(fa.y) << 16) | f2bf(fa.x);
      pk.y = ((unsigned)f2bf(fa.w) << 16) | f2bf(fa.z);
      pk.z = ((unsigned)f2bf(fb.y) << 16) | f2bf(fb.x);
      pk.w = ((unsigned)f2bf(fb.w) << 16) | f2bf(fb.z);
      *(uint4*)(As + arow * APAD + s * 8) = pk;
    }
    __syncthreads();
#pragma unroll
    for (int kk = 0; kk < 4; kk++) {
      s16x8 af[2], bf4[4];
#pragma unroll
      for (int m = 0; m < 2; m++) {
        int r = wr + m * 16 + l15;
        af[m] = *(const s16x8*)(As + r * APAD + (kk * 4 + q) * 8);
      }
#pragma unroll
      for (int n = 0; n < 4; n++) {
        int rB = wc + n * 16 + l15;
        int slot = (kk * 4 + q) ^ l15;      // rB&15 == l15
        bf4[n] = *(const s16x8*)(Bs + rB * 128 + slot * 8);
      }
#pragma unroll
      for (int m = 0; m < 2; m++)
#pragma unroll
        for (int n = 0; n < 4; n++)
          acc[m][n] = __builtin_amdgcn_mfma_f32_16x16x32_bf16(af[m], bf4[n], acc[m][n], 0, 0, 0);
    }
    __syncthreads();
  }

  const int cbase = col0 + wc + l15;
  const int rq = (lane >> 4) * 4;
  const int hd = (col0 + wc) >> 6;   // head owned by this wave
  float alc[4], arc[4];
#pragma unroll
  for (int n = 0; n < 4; n++) { alc[n] = al[cbase + n * 16]; arc[n] = ar[cbase + n * 16]; }

#pragma unroll
  for (int m = 0; m < 2; m++) {
#pragma unroll
    for (int r = 0; r < 4; r++) {
      int grow = row0 + wr + m * 16 + rq + r;
      float a = 0.f, b = 0.f;
#pragma unroll
      for (int n = 0; n < 4; n++) {
        float v = acc[m][n][r];
        a += v * alc[n];
        b += v * arc[n];
      }
      a += __shfl_xor(a, 1, 64); a += __shfl_xor(a, 2, 64);
      a += __shfl_xor(a, 4, 64); a += __shfl_xor(a, 8, 64);
      b += __shfl_xor(b, 1, 64); b += __shfl_xor(b, 2, 64);
      b += __shfl_xor(b, 4, 64); b += __shfl_xor(b, 8, 64);
      if (grow < NN) {
        unsigned short* dp = outb + (size_t)grow * NHD + cbase;
#pragma unroll
        for (int n = 0; n < 4; n++) dp[n * 16] = f2bf(acc[m][n][r]);
        if (l15 == 0) {
          el[(size_t)grow * NH + hd] = a;
          er[(size_t)grow * NH + hd] = b;
        }
      }
    }
  }
}

// ---------------- semantic GEMM with fused tanh*w2 row-reduce ----------------
__global__ __launch_bounds__(256, 2) void k_gemm_sem(const unsigned short* __restrict__ A0,
                                                     const unsigned short* __restrict__ A1,
                                                     const unsigned short* __restrict__ Bt,
                                                     const float* __restrict__ b1,
                                                     const float* __restrict__ w2,
                                                     float* __restrict__ scal) {
  __shared__ unsigned short As[128 * 32];
  __shared__ unsigned short Bs[128 * 32];
  __shared__ float rsum[2][128];
  __shared__ float pp[2][2];
  const int M = 2 * CC;
  const int tid = threadIdx.x;
  const int wv = tid >> 6, lane = tid & 63;
  const int row0 = blockIdx.x * 128;
  const int wr = (wv >> 1) * 64, wc = (wv & 1) * 64;
  const int ci = lane & 3, rsub = lane >> 2;

  f32x4 acc[4][4] = {};

  const int l15 = lane & 15;
  const int pc = (((lane >> 4) ^ ((l15 >> 1) & 3))) * 8;

  for (int k0 = 0; k0 < NHD; k0 += 32) {
#pragma unroll
    for (int i = 0; i < 2; i++) {
      int lrow = (wv * 2 + i) * 16 + rsub;
      int kc = (ci ^ ((lrow >> 1) & 3)) << 3;
      int ga = row0 + lrow; if (ga > M - 1) ga = M - 1;
      const unsigned short* Ap = (ga < CC) ? A0 + (size_t)ga * NHD
                                           : A1 + (size_t)(ga - CC) * NHD;
      gl_lds16(Ap + k0 + kc, As + (wv * 2 + i) * 512);
      int gb = lrow;  // col0 = 0, Nb = 128
      gl_lds16(Bt + (size_t)gb * NHD + k0 + kc, Bs + (wv * 2 + i) * 512);
    }
    __syncthreads();
    s16x8 af[4], bf[4];
#pragma unroll
    for (int m = 0; m < 4; m++) {
      af[m] = *(const s16x8*)(As + (wr + m * 16 + l15) * 32 + pc);
      bf[m] = *(const s16x8*)(Bs + (wc + m * 16 + l15) * 32 + pc);
    }
#pragma unroll
    for (int m = 0; m < 4; m++)
#pragma unroll
      for (int n = 0; n < 4; n++)
        acc[m][n] = __builtin_amdgcn_mfma_f32_16x16x32_bf16(af[m], bf[n], acc[m][n], 0, 0, 0);
    __syncthreads();
  }

  if (tid < 128) { rsum[0][tid] = 0.f; rsum[1][tid] = 0.f; }
  __syncthreads();
  const int cb = wc + l15;
  const int rq = (lane >> 4) * 4;
  float b1c[4], w2c[4];
#pragma unroll
  for (int n = 0; n < 4; n++) { b1c[n] = b1[cb + n * 16]; w2c[n] = w2[cb + n * 16]; }
#pragma unroll
  for (int m = 0; m < 4; m++) {
#pragma unroll
    for (int r = 0; r < 4; r++) {
      int rl = wr + m * 16 + rq + r;
      float s = 0.f;
#pragma unroll
      for (int n = 0; n < 4; n++) s += tanhf(acc[m][n][r] + b1c[n]) * w2c[n];
      s += __shfl_xor(s, 1, 64); s += __shfl_xor(s, 2, 64);
      s += __shfl_xor(s, 4, 64); s += __shfl_xor(s, 8, 64);
      if (l15 == 0 && row0 + rl < M) rsum[wv & 1][rl] = s;
    }
  }
  __syncthreads();
  if (tid < 128) {
    int grow = row0 + tid;
    float v = rsum[0][tid] + rsum[1][tid];
    float vA = (grow < CC) ? v : 0.f;
    float vB = (grow >= CC && grow < M) ? v : 0.f;
#pragma unroll
    for (int off = 32; off > 0; off >>= 1) {
      vA += __shfl_xor(vA, off, 64);
      vB += __shfl_xor(vB, off, 64);
    }
    if ((tid & 63) == 0) { pp[tid >> 6][0] = vA; pp[tid >> 6][1] = vB; }
  }
  __syncthreads();
  if (tid == 0) {
    atomicAdd(scal + 0, pp[0][0] + pp[1][0]);
    atomicAdd(scal + 1, pp[0][1] + pp[1][1]);
  }
}

// ---------------- batched CSR build (3 graphs), bucket-staged scatter ----------------
__global__ void k_hist3(const int* __restrict__ d0, const int* __restrict__ d1,
                        const int* __restrict__ d2, int* __restrict__ deg3) {
  int e = blockIdx.x * 256 + threadIdx.x;
  int g = blockIdx.y;
  const int* dst = (g == 0) ? d0 : (g == 1) ? d1 : d2;
  atomicAdd(deg3 + g * NN + dst[e], 1);
}

__global__ __launch_bounds__(1024) void k_scan3(const int* __restrict__ deg3,
                                                int* __restrict__ rowptr3,
                                                int* __restrict__ curB) {
  __shared__ int part[1024];
  const int g = blockIdx.x;
  const int* deg = deg3 + g * NN;
  int* rowptr = rowptr3 + g * (NN + 1);
  int tid = threadIdx.x;
  const int CH = 20;
  int base = tid * CH;
  int s = 0;
  for (int i = 0; i < CH; i++) { int idx = base + i; if (idx < NN) s += deg[idx]; }
  part[tid] = s;
  __syncthreads();
  for (int off = 1; off < 1024; off <<= 1) {
    int u = (tid >= off) ? part[tid - off] : 0;
    int v = part[tid];
    __syncthreads();
    part[tid] = u + v;
    __syncthreads();
  }
  int run = (tid == 0) ? 0 : part[tid - 1];
  for (int i = 0; i < CH; i++) {
    int idx = base + i;
    if (idx < NN) {
      rowptr[idx] = run;
      if ((idx & 255) == 0) curB[g * (NBKT + 1) + (idx >> 8)] = run;
      run += deg[idx];
    }
  }
  if (tid == 1023) rowptr[NN] = part[1023];
}

__global__ __launch_bounds__(1024) void k_coarse(const int* __restrict__ s0,
                                                 const int* __restrict__ s1,
                                                 const int* __restrict__ s2,
                                                 const int* __restrict__ d0,
                                                 const int* __restrict__ d1,
                                                 const int* __restrict__ d2,
                                                 int* __restrict__ curB,
                                                 unsigned* __restrict__ staging) {
  __shared__ int bcnt[NBKT];
  __shared__ int bbase[NBKT];
  int g = blockIdx.y;
  const int* src = (g == 0) ? s0 : (g == 1) ? s1 : s2;
  const int* dst = (g == 0) ? d0 : (g == 1) ? d1 : d2;
  int tid = threadIdx.x;
  if (tid < NBKT) bcnt[tid] = 0;
  __syncthreads();
  int e = blockIdx.x * 1024 + tid;
  bool val = e < NE;
  int b = 0, r = 0, sv = 0, dv = 0;
  if (val) {
    dv = dst[e]; sv = src[e];
    b = dv >> 8;
    r = atomicAdd(&bcnt[b], 1);
  }
  __syncthreads();
  if (tid < NBKT && bcnt[tid] > 0) bbase[tid] = atomicAdd(&curB[g * (NBKT + 1) + tid], bcnt[tid]);
  __syncthreads();
  if (val) staging[(size_t)g * NE + bbase[b] + r] = ((unsigned)sv << 8) | (unsigned)(dv & 255);
}

__global__ __launch_bounds__(1024) void k_fine(const int* __restrict__ rowptr3,
                                               const unsigned* __restrict__ staging,
                                               unsigned short* __restrict__ srcord3) {
  __shared__ int cur[256];
  int g = blockIdx.y, b = blockIdx.x;
  const int* rowptr = rowptr3 + g * (NN + 1);
  int n0 = b << 8;
  int tid = threadIdx.x;
  if (tid < 256) {
    int node = n0 + tid;
    cur[tid] = (node < NN) ? rowptr[node] : 0;
  }
  __syncthreads();
  int nend = n0 + 256; if (nend > NN) nend = NN;
  int start = rowptr[n0];
  int endp = rowptr[nend];
  for (int i = start + tid; i < endp; i += 1024) {
    unsigned u = staging[(size_t)g * NE + i];
    int nl = u & 255;
    int pos = atomicAdd(&cur[nl], 1);
    srcord3[(size_t)g * NE + pos] = (unsigned short)(u >> 8);
  }
}

// ---------------- FUSED softmax + gather agg + bias + elu, 3 graphs batched ----------------
// blockIdx.y = graph; wave per node; lane = 16B slice, head = lane>>3.
__global__ __launch_bounds__(256) void k_aggf3(const int* __restrict__ rowptr3,
                                               const unsigned short* __restrict__ srcord3,
                                               const float* __restrict__ el3,
                                               const float* __restrict__ er3,
                                               const unsigned short* __restrict__ hb3,
                                               const float* __restrict__ b0p,
                                               const float* __restrict__ b1p,
                                               const float* __restrict__ b2p,
                                               unsigned short* __restrict__ ob3) {
  __shared__ float aS[4][64 * 8];
  __shared__ int sS[4][64];
  int g = blockIdx.y;
  const int* rowptr = rowptr3 + g * (NN + 1);
  const unsigned short* srcord = srcord3 + (size_t)g * NE;
  const float* el = el3 + (size_t)g * NN * NH;
  const float* er = er3 + (size_t)g * NN * NH;
  const unsigned short* hb = hb3 + (size_t)g * NN * NHD;
  const float* bias = (g == 0) ? b0p : (g == 1) ? b1p : b2p;
  unsigned short* ob = ob3 + (size_t)g * NN * NHD;

  int wv = threadIdx.x >> 6;
  int t = (blockIdx.x * 256 + threadIdx.x) >> 6;
  int lane = threadIdx.x & 63;
  int h = lane >> 3;
  int beg = rowptr[t], end = rowptr[t + 1];

  float4 er0 = ((const float4*)(er + (size_t)t * NH))[0];
  float4 er1 = ((const float4*)(er + (size_t)t * NH))[1];
  float erow[8] = {er0.x, er0.y, er0.z, er0.w, er1.x, er1.y, er1.z, er1.w};

  float acc[8] = {0.f, 0.f, 0.f, 0.f, 0.f, 0.f, 0.f, 0.f};
  float den = 0.f;

  for (int cbeg = beg; cbeg < end; cbeg += 64) {
    int cnt = end - cbeg; if (cnt > 64) cnt = 64;
    bool valid = lane < cnt;
    int pidx = cbeg + lane; if (pidx > end - 1) pidx = end - 1;
    int s = srcord[pidx];
    if (valid) {
      sS[wv][lane] = s;
      float4 a0 = ((const float4*)(el + (size_t)s * NH))[0];
      float4 a1 = ((const float4*)(el + (size_t)s * NH))[1];
      float v[8] = {a0.x + erow[0], a0.y + erow[1], a0.z + erow[2], a0.w + erow[3],
                    a1.x + erow[4], a1.y + erow[5], a1.z + erow[6], a1.w + erow[7]};
#pragma unroll
      for (int k = 0; k < 8; k++) {
        float x = v[k];
        x = x >= 0.f ? x : 0.2f * x;
        aS[wv][lane * 8 + k] = __expf(x);
      }
    }
    const unsigned short* hbl = hb + lane * 8;
    int q = 0;
    for (; q + 3 < cnt; q += 4) {
      int s0 = sS[wv][q], s1 = sS[wv][q + 1], s2 = sS[wv][q + 2], s3 = sS[wv][q + 3];
      float w0 = aS[wv][q * 8 + h];
      float w1 = aS[wv][(q + 1) * 8 + h];
      float w2 = aS[wv][(q + 2) * 8 + h];
      float w3 = aS[wv][(q + 3) * 8 + h];
      uint4 v0 = *(const uint4*)(hbl + (size_t)s0 * NHD);
      uint4 v1 = *(const uint4*)(hbl + (size_t)s1 * NHD);
      uint4 v2 = *(const uint4*)(hbl + (size_t)s2 * NHD);
      uint4 v3 = *(const uint4*)(hbl + (size_t)s3 * NHD);
      den += (w0 + w1) + (w2 + w3);
      acc[0] += w0 * bflo(v0.x); acc[1] += w0 * bfhi(v0.x);
      acc[2] += w0 * bflo(v0.y); acc[3] += w0 * bfhi(v0.y);
      acc[4] += w0 * bflo(v0.z); acc[5] += w0 * bfhi(v0.z);
      acc[6] += w0 * bflo(v0.w); acc[7] += w0 * bfhi(v0.w);
      acc[0] += w1 * bflo(v1.x); acc[1] += w1 * bfhi(v1.x);
      acc[2] += w1 * bflo(v1.y); acc[3] += w1 * bfhi(v1.y);
      acc[4] += w1 * bflo(v1.z); acc[5] += w1 * bfhi(v1.z);
      acc[6] += w1 * bflo(v1.w); acc[7] += w1 * bfhi(v1.w);
      acc[0] += w2 * bflo(v2.x); acc[1] += w2 * bfhi(v2.x);
      acc[2] += w2 * bflo(v2.y); acc[3] += w2 * bfhi(v2.y);
      acc[4] += w2 * bflo(v2.z); acc[5] += w2 * bfhi(v2.z);
      acc[6] += w2 * bflo(v2.w); acc[7] += w2 * bfhi(v2.w);
      acc[0] += w3 * bflo(v3.x); acc[1] += w3 * bfhi(v3.x);
      acc[2] += w3 * bflo(v3.y); acc[3] += w3 * bfhi(v3.y);
      acc[4] += w3 * bflo(v3.z); acc[5] += w3 * bfhi(v3.z);
      acc[6] += w3 * bflo(v3.w); acc[7] += w3 * bfhi(v3.w);
    }
    for (; q < cnt; q++) {
      int s0 = sS[wv][q];
      float w0 = aS[wv][q * 8 + h];
      uint4 v0 = *(const uint4*)(hbl + (size_t)s0 * NHD);
      den += w0;
      acc[0] += w0 * bflo(v0.x); acc[1] += w0 * bfhi(v0.x);
      acc[2] += w0 * bflo(v0.y); acc[3] += w0 * bfhi(v0.y);
      acc[4] += w0 * bflo(v0.z); acc[5] += w0 * bfhi(v0.z);
      acc[6] += w0 * bflo(v0.w); acc[7] += w0 * bfhi(v0.w);
    }
  }

  float dn = 1.f / fmaxf(den, 1e-9f);
  float4 b0 = ((const float4*)(bias + lane * 8))[0];
  float4 b1 = ((const float4*)(bias + lane * 8))[1];
  float r[8];
  r[0] = acc[0] * dn + b0.x; r[1] = acc[1] * dn + b0.y;
  r[2] = acc[2] * dn + b0.z; r[3] = acc[3] * dn + b0.w;
  r[4] = acc[4] * dn + b1.x; r[5] = acc[5] * dn + b1.y;
  r[6] = acc[6] * dn + b1.z; r[7] = acc[7] * dn + b1.w;
#pragma unroll
  for (int j = 0; j < 8; j++) r[j] = r[j] > 0.f ? r[j] : expm1f(r[j]);
  uint4 z;
  z.x = ((unsigned)f2bf(r[1]) << 16) | f2bf(r[0]);
  z.y = ((unsigned)f2bf(r[3]) << 16) | f2bf(r[2]);
  z.z = ((unsigned)f2bf(r[5]) << 16) | f2bf(r[4]);
  z.w = ((unsigned)f2bf(r[7]) << 16) | f2bf(r[6]);
  *(uint4*)(ob + (size_t)t * NHD + lane * 8) = z;
}

// stage 1: sound(bf16) = beta0*zA(bf16) + beta1*zB(bf16)
__global__ void k_combine_s1(const float* __restrict__ scal,
                             const unsigned short* __restrict__ zA,
                             const unsigned short* __restrict__ zB,
                             unsigned short* __restrict__ outb) {
  int i = blockIdx.x * 256 + threadIdx.x;   // grid exact CC*NHD/4
  float w0 = scal[0] * (1.f / CC), w1v = scal[1] * (1.f / CC);
  float mx = fmaxf(w0, w1v);
  float e0 = expf(w0 - mx), e1 = expf(w1v - mx);
  float inv = 1.f / (e0 + e1);
  float b0 = e0 * inv, b1v = e1 * inv;
  ushort4 a = ((const ushort4*)zA)[i];
  ushort4 b = ((const ushort4*)zB)[i];
  ushort4 z;
  z.x = f2bf(b0 * bf2f(a.x) + b1v * bf2f(b.x));
  z.y = f2bf(b0 * bf2f(a.y) + b1v * bf2f(b.y));
  z.z = f2bf(b0 * bf2f(a.z) + b1v * bf2f(b.z));
  z.w = f2bf(b0 * bf2f(a.w) + b1v * bf2f(b.w));
  ((ushort4*)outb)[i] = z;
}

// ---------------- fused stage-2 combine + final head-means (bf16 inputs) ----------------
__global__ void k_comb2_means(const float* __restrict__ scal,
                              const unsigned short* __restrict__ zsound,
                              const unsigned short* __restrict__ ob0,
                              const unsigned short* __restrict__ ob1,
                              const unsigned short* __restrict__ ob2,
                              float* __restrict__ outf,
                              float* __restrict__ m1, float* __restrict__ m2,
                              float* __restrict__ m3) {
  int idx = blockIdx.x * 256 + threadIdx.x;   // grid exact NN*64
  int n = idx >> 6, d = idx & 63;
  if (n < CC) {
    float w0 = scal[0] * (1.f / CC), w1v = scal[1] * (1.f / CC);
    float mx = fmaxf(w0, w1v);
    float e0 = expf(w0 - mx), e1 = expf(w1v - mx);
    float inv = 1.f / (e0 + e1);
    float b0 = e0 * inv, b1v = e1 * inv;
    const unsigned short* zs = zsound + (size_t)n * NHD + d;
    const unsigned short* p1 = ob1 + (size_t)n * NHD + d;
    float* po = outf + (size_t)n * NHD + d;
    float v = 0.f;
#pragma unroll
    for (int h = 0; h < 8; h++) {
      float r = b0 * bf2f(zs[h * 64]) + b1v * bf2f(p1[h * 64]);
      po[h * 64] = r;
      v += r;
    }
    v *= 0.125f;
    m1[idx] = v; m2[idx] = v; m3[idx] = v;
  } else {
    const unsigned short* p0 = ob0 + (size_t)n * NHD + d;
    const unsigned short* p1 = ob1 + (size_t)n * NHD + d;
    const unsigned short* p2 = ob2 + (size_t)n * NHD + d;
    float v0 = 0.f, v1 = 0.f, v2 = 0.f;
#pragma unroll
    for (int h = 0; h < 8; h++) {
      v0 += bf2f(p0[h * 64]); v1 += bf2f(p1[h * 64]); v2 += bf2f(p2[h * 64]);
    }
    m1[idx] = v0 * 0.125f; m2[idx] = v1 * 0.125f; m3[idx] = v2 * 0.125f;
  }
}

extern "C" void kernel_launch(void* const* d_in, const int* in_sizes, int n_in,
                              void* d_out, int out_size, void* d_ws, size_t ws_size,
                              hipStream_t stream) {
  (void)in_sizes; (void)n_in; (void)out_size; (void)ws_size;

  const float* feat[3]; const int* srcp[3]; const int* dstp[3];
  const float* Wp[3]; const float* alp[3]; const float* arp[3]; const float* bp[3];
  for (int g = 0; g < 3; g++) {
    const int base = g * 8;  // dict order: feat,src,dst,char,W,al,ar,b
    feat[g] = (const float*)d_in[base + 0];
    srcp[g] = (const int*)d_in[base + 1];
    dstp[g] = (const int*)d_in[base + 2];
    Wp[g]   = (const float*)d_in[base + 4];
    alp[g]  = (const float*)d_in[base + 5];
    arp[g]  = (const float*)d_in[base + 6];
    bp[g]   = (const float*)d_in[base + 7];
  }
  const float* sw1 = (const float*)d_in[24];
  const float* sb1 = (const float*)d_in[25];
  const float* sw2 = (const float*)d_in[26];
  const float* aw1 = (const float*)d_in[27];
  const float* ab1 = (const float*)d_in[28];
  const float* aw2 = (const float*)d_in[29];

  char* wsp = (char*)d_ws;
  auto alloc = [&](size_t bytes) {
    char* p = wsp;
    wsp += (bytes + 255) & ~(size_t)255;
    return p;
  };
  // total ~150 MB (proven-safe >= 229 MB from round 2)
  unsigned short* ob3 = (unsigned short*)alloc((size_t)3 * NN * NHD * 2);   // 61.5 MB
  unsigned short* hb3 = (unsigned short*)alloc((size_t)3 * NN * NHD * 2);   // 61.5 MB
  unsigned short* wtb3 = (unsigned short*)alloc((size_t)3 * WTB_SZ * 2);
  unsigned short* w1tb2 = (unsigned short*)alloc((size_t)2 * W1TB_SZ * 2);
  unsigned short* sound = (unsigned short*)alloc((size_t)CC * NHD * 2);
  float* el3 = (float*)alloc((size_t)3 * NN * NH * 4);
  float* er3 = (float*)alloc((size_t)3 * NN * NH * 4);
  float* scal = (float*)alloc(256);
  int* deg3 = (int*)alloc((size_t)3 * NN * 4);
  int* rowptr3 = (int*)alloc((size_t)3 * (NN + 1) * 4 + 64);
  int* curB = (int*)alloc((size_t)3 * (NBKT + 1) * 4);
  unsigned* staging = (unsigned*)alloc((size_t)3 * NE * 4);
  unsigned short* srcord3 = (unsigned short*)alloc((size_t)3 * NE * 2);

  unsigned short* ob0 = ob3;
  unsigned short* ob1 = ob3 + (size_t)NN * NHD;
  unsigned short* ob2 = ob3 + (size_t)2 * NN * NHD;

  float* outf = (float*)d_out;
  float* outm1 = outf + (size_t)CC * NHD;
  float* outm2 = outm1 + (size_t)NN * ND;
  float* outm3 = outm2 + (size_t)NN * ND;

  // ---- prep + CSR build (5 dispatches) ----
  const int PREP_T = 3 * WTB_SZ + 2 * W1TB_SZ + 3 * NN + 4;
  k_prep<<<(PREP_T + 255) / 256, 256, 0, stream>>>(Wp[0], Wp[1], Wp[2], sw1, aw1,
                                                   wtb3, w1tb2, deg3, scal);
  k_hist3<<<dim3(NE / 256, 3), 256, 0, stream>>>(dstp[0], dstp[1], dstp[2], deg3);
  k_scan3<<<3, 1024, 0, stream>>>(deg3, rowptr3, curB);
  k_coarse<<<dim3((NE + 1023) / 1024, 3), 1024, 0, stream>>>(
      srcp[0], srcp[1], srcp[2], dstp[0], dstp[1], dstp[2], curB, staging);
  k_fine<<<dim3(NBKT, 3), 1024, 0, stream>>>(rowptr3, staging, srcord3);

  // ---- all 3 GAT layers batched: one GEMM launch + one agg launch ----
  k_gemm_gat3<<<3 * GB, 256, 0, stream>>>(feat[0], feat[1], feat[2], wtb3, hb3,
                                          alp[0], alp[1], alp[2], arp[0], arp[1], arp[2],
                                          el3, er3);
  k_aggf3<<<dim3(NN * 64 / 256, 3), 256, 0, stream>>>(rowptr3, srcord3, el3, er3, hb3,
                                                      bp[0], bp[1], bp[2], ob3);

  // ---- semantic stage 1: rows<CC from ob0, rows>=CC from ob2 -> sound ----
  k_gemm_sem<<<(2 * CC + 127) / 128, 256, 0, stream>>>(ob0, ob2, w1tb2, sb1, sw2, scal);
  k_combine_s1<<<CC * NHD / 4 / 256, 256, 0, stream>>>(scal, ob0, ob2, sound);

  // ---- semantic stage 2: rows<CC from sound, rows>=CC from ob1 -> combine+means ----
  k_gemm_sem<<<(2 * CC + 127) / 128, 256, 0, stream>>>(sound, ob1, w1tb2 + W1TB_SZ, ab1, aw2, scal + 2);
  k_comb2_means<<<NN * 64 / 256, 256, 0, stream>>>(scal + 2, sound, ob0, ob1, ob2,
                                                   outf, outm1, outm2, outm3);
}

// Round 23
// 399.749 us; speedup vs baseline: 1.1658x; 1.0280x over previous
//
#include <hip/hip_runtime.h>
#include <math.h>

#define NN 20000
#define NE 320000
#define CC 10000
#define KIN 768
#define NH 8
#define ND 64
#define NHD 512
#define NSA 128
#define NBKT 79                 // buckets of 256 nodes: 79*256 = 20224 >= NN

#define WTB_SZ (NHD * KIN)      // 393216 per graph
#define W1TB_SZ (NSA * NHD)     // 65536 per stage
#define APAD 136                // A LDS row stride (bf16) in gat gemm
#define GB 1280                 // gemm blocks per graph

typedef __attribute__((ext_vector_type(4))) float f32x4;
typedef __attribute__((ext_vector_type(8))) short s16x8;

__device__ __forceinline__ unsigned short f2bf(float f) {
  unsigned u = __float_as_uint(f);
  u += 0x7fffu + ((u >> 16) & 1u);
  return (unsigned short)(u >> 16);
}
__device__ __forceinline__ float bf2f(unsigned short s) {
  return __uint_as_float(((unsigned)s) << 16);
}
__device__ __forceinline__ float bflo(unsigned u) { return __uint_as_float(u << 16); }
__device__ __forceinline__ float bfhi(unsigned u) { return __uint_as_float(u & 0xffff0000u); }

__device__ __forceinline__ void gl_lds16(const void* g, void* l) {
  __builtin_amdgcn_global_load_lds(
      (const __attribute__((address_space(1))) unsigned int*)g,
      (__attribute__((address_space(3))) unsigned int*)l, 16, 0, 0);
}

// ---------------- prep: all weight transposes + zero deg3 + zero scal ----------------
__global__ void k_prep(const float* __restrict__ W0, const float* __restrict__ W1,
                       const float* __restrict__ W2, const float* __restrict__ sw1,
                       const float* __restrict__ aw1, unsigned short* __restrict__ wtb3,
                       unsigned short* __restrict__ w1tb2, int* __restrict__ deg3,
                       float* __restrict__ scal) {
  int i = blockIdx.x * 256 + threadIdx.x;
  if (i < 3 * WTB_SZ) {
    int g = i / WTB_SZ;
    int j = i - g * WTB_SZ;
    int n = j / KIN, k = j - n * KIN;
    const float* W = (g == 0) ? W0 : (g == 1) ? W1 : W2;
    wtb3[i] = f2bf(W[(size_t)k * NHD + n]);
    return;
  }
  i -= 3 * WTB_SZ;
  if (i < 2 * W1TB_SZ) {
    int p = i / W1TB_SZ;
    int j = i - p * W1TB_SZ;
    int n = j / NHD, k = j - n * NHD;
    const float* W = p ? aw1 : sw1;
    w1tb2[p * W1TB_SZ + n * NHD + k] = f2bf(W[(size_t)k * NSA + n]);
    return;
  }
  i -= 2 * W1TB_SZ;
  if (i < 3 * NN) { deg3[i] = 0; return; }
  i -= 3 * NN;
  if (i < 4) scal[i] = 0.f;
}

// ---------------- GAT GEMM, 3 graphs batched ----------------
__global__ __launch_bounds__(256, 2) void k_gemm_gat3(
    const float* __restrict__ f0, const float* __restrict__ f1, const float* __restrict__ f2,
    const unsigned short* __restrict__ wtb3, unsigned short* __restrict__ hb3,
    const float* __restrict__ al0, const float* __restrict__ al1, const float* __restrict__ al2,
    const float* __restrict__ ar0, const float* __restrict__ ar1, const float* __restrict__ ar2,
    float* __restrict__ el3, float* __restrict__ er3) {
  __shared__ unsigned short As[64 * APAD];    // 17.4 KB
  __shared__ unsigned short Bs[128 * 128];    // 32 KB
  const int bidg = blockIdx.x;
  const int g = bidg / GB;
  const int bid = bidg - g * GB;
  const int xcd = bidg & 7, t = bid >> 3;     // bid&7 == bidg&7 (GB % 8 == 0)
  const int rowblk = (t >> 2) * 8 + xcd;
  if (rowblk * 64 >= NN) return;
  const float* A = (g == 0) ? f0 : (g == 1) ? f1 : f2;
  const float* al = (g == 0) ? al0 : (g == 1) ? al1 : al2;
  const float* ar = (g == 0) ? ar0 : (g == 1) ? ar1 : ar2;
  const unsigned short* Bt = wtb3 + (size_t)g * WTB_SZ;
  unsigned short* outb = hb3 + (size_t)g * NN * NHD;
  float* el = el3 + (size_t)g * NN * NH;
  float* er = er3 + (size_t)g * NN * NH;

  const int row0 = rowblk * 64;
  const int col0 = (t & 3) * 128;
  const int tid = threadIdx.x;
  const int wv = tid >> 6, lane = tid & 63;
  const int wr = (wv & 1) * 32, wc = (wv >> 1) * 64;

  f32x4 acc[2][4] = {};

  const int l15 = lane & 15;
  const int q = lane >> 4;              // 0..3 (k-chunk within 32-k subtile)

  const int arow = tid >> 2, ci = tid & 3;
  int aga = row0 + arow; if (aga > NN - 1) aga = NN - 1;
  const float* ap = A + (size_t)aga * KIN;

  const int binrow = lane >> 4, bch = lane & 15;

  for (int k0 = 0; k0 < KIN; k0 += 128) {
#pragma unroll
    for (int j = 0; j < 8; j++) {
      int rb0 = (wv * 8 + j) * 4;
      int grow = col0 + rb0 + binrow;     // always < 512
      int srcch = bch ^ ((j & 3) * 4 + binrow);
      gl_lds16(Bt + (size_t)grow * KIN + k0 + srcch * 8, Bs + rb0 * 128);
    }
#pragma unroll
    for (int sc = 0; sc < 4; sc++) {
      int s = ci + sc * 4;
      const float* sp = ap + k0 + s * 8;
      float4 fa = ((const float4*)sp)[0];
      float4 fb = ((const float4*)sp)[1];
      uint4 pk;
      pk.x = ((unsigned)f2bf(fa.y) << 16) | f2bf(fa.x);
      pk.y = ((unsigned)f2bf(fa.w) << 16) | f2bf(fa.z);
      pk.z = ((unsigned)f2bf(fb.y) << 16) | f2bf(fb.x);
      pk.w = ((unsigned)f2bf(fb.w) << 16) | f2bf(fb.z);
      *(uint4*)(As + arow * APAD + s * 8) = pk;
    }
    __syncthreads();
#pragma unroll
    for (int kk = 0; kk < 4; kk++) {
      s16x8 af[2], bf4[4];
#pragma unroll
      for (int m = 0; m < 2; m++) {
        int r = wr + m * 16 + l15;
        af[m] = *(const s16x8*)(As + r * APAD + (kk * 4 + q) * 8);
      }
#pragma unroll
      for (int n = 0; n < 4; n++) {
        int rB = wc + n * 16 + l15;
        int slot = (kk * 4 + q) ^ l15;      // rB&15 == l15
        bf4[n] = *(const s16x8*)(Bs + rB * 128 + slot * 8);
      }
#pragma unroll
      for (int m = 0; m < 2; m++)
#pragma unroll
        for (int n = 0; n < 4; n++)
          acc[m][n] = __builtin_amdgcn_mfma_f32_16x16x32_bf16(af[m], bf4[n], acc[m][n], 0, 0, 0);
    }
    __syncthreads();
  }

  const int cbase = col0 + wc + l15;
  const int rq = (lane >> 4) * 4;
  const int hd = (col0 + wc) >> 6;   // head owned by this wave
  float alc[4], arc[4];
#pragma unroll
  for (int n = 0; n < 4; n++) { alc[n] = al[cbase + n * 16]; arc[n] = ar[cbase + n * 16]; }

#pragma unroll
  for (int m = 0; m < 2; m++) {
#pragma unroll
    for (int r = 0; r < 4; r++) {
      int grow = row0 + wr + m * 16 + rq + r;
      float a = 0.f, b = 0.f;
#pragma unroll
      for (int n = 0; n < 4; n++) {
        float v = acc[m][n][r];
        a += v * alc[n];
        b += v * arc[n];
      }
      a += __shfl_xor(a, 1, 64); a += __shfl_xor(a, 2, 64);
      a += __shfl_xor(a, 4, 64); a += __shfl_xor(a, 8, 64);
      b += __shfl_xor(b, 1, 64); b += __shfl_xor(b, 2, 64);
      b += __shfl_xor(b, 4, 64); b += __shfl_xor(b, 8, 64);
      if (grow < NN) {
        unsigned short* dp = outb + (size_t)grow * NHD + cbase;
#pragma unroll
        for (int n = 0; n < 4; n++) dp[n * 16] = f2bf(acc[m][n][r]);
        if (l15 == 0) {
          el[(size_t)grow * NH + hd] = a;
          er[(size_t)grow * NH + hd] = b;
        }
      }
    }
  }
}

// ---------------- semantic GEMM, 64x128 tiles (313 blocks), fused tanh*w2 reduce ----------------
// Both operands async gl_lds16 (bf16) with the chunk^(row&15) involution; BK=128.
// A rows: row<CC from A0[row], else A1[row-CC]. Accumulates scal[0]/scal[1].
__global__ __launch_bounds__(256, 2) void k_gemm_sem64(const unsigned short* __restrict__ A0,
                                                       const unsigned short* __restrict__ A1,
                                                       const unsigned short* __restrict__ Bt,
                                                       const float* __restrict__ b1,
                                                       const float* __restrict__ w2,
                                                       float* __restrict__ scal) {
  __shared__ unsigned short As[64 * 128];     // 16 KB
  __shared__ unsigned short Bs[128 * 128];    // 32 KB
  __shared__ float rsum[2][64];
  const int M = 2 * CC;
  const int row0 = blockIdx.x * 64;
  const int tid = threadIdx.x;
  const int wv = tid >> 6, lane = tid & 63;
  const int wr = (wv & 1) * 32, wc = (wv >> 1) * 64;

  f32x4 acc[2][4] = {};

  const int l15 = lane & 15;
  const int q = lane >> 4;
  const int binrow = lane >> 4, bch = lane & 15;

  for (int k0 = 0; k0 < NHD; k0 += 128) {
    // A: 4 async issues per wave (rows (wv*4+j)*4 .. +4 of the 64-row tile)
#pragma unroll
    for (int j = 0; j < 4; j++) {
      int rb0 = (wv * 4 + j) * 4;
      int ga = row0 + rb0 + binrow; if (ga > M - 1) ga = M - 1;
      const unsigned short* Ap = (ga < CC) ? A0 + (size_t)ga * NHD
                                           : A1 + (size_t)(ga - CC) * NHD;
      int srcch = bch ^ ((j & 3) * 4 + binrow);
      gl_lds16(Ap + k0 + srcch * 8, As + rb0 * 128);
    }
    // B: 8 async issues per wave (128 rows)
#pragma unroll
    for (int j = 0; j < 8; j++) {
      int rb0 = (wv * 8 + j) * 4;
      int grow = rb0 + binrow;            // Nb = 128
      int srcch = bch ^ ((j & 3) * 4 + binrow);
      gl_lds16(Bt + (size_t)grow * NHD + k0 + srcch * 8, Bs + rb0 * 128);
    }
    __syncthreads();
#pragma unroll
    for (int kk = 0; kk < 4; kk++) {
      s16x8 af[2], bf4[4];
#pragma unroll
      for (int m = 0; m < 2; m++) {
        int r = wr + m * 16 + l15;
        int slot = (kk * 4 + q) ^ l15;    // r&15 == l15
        af[m] = *(const s16x8*)(As + r * 128 + slot * 8);
      }
#pragma unroll
      for (int n = 0; n < 4; n++) {
        int rB = wc + n * 16 + l15;
        int slot = (kk * 4 + q) ^ l15;
        bf4[n] = *(const s16x8*)(Bs + rB * 128 + slot * 8);
      }
#pragma unroll
      for (int m = 0; m < 2; m++)
#pragma unroll
        for (int n = 0; n < 4; n++)
          acc[m][n] = __builtin_amdgcn_mfma_f32_16x16x32_bf16(af[m], bf4[n], acc[m][n], 0, 0, 0);
    }
    __syncthreads();
  }

  // epilogue: per-row sum of tanh(acc + b1[c]) * w2[c] over this wave's 64 cols
  if (tid < 64) { rsum[0][tid] = 0.f; rsum[1][tid] = 0.f; }
  __syncthreads();
  const int cb = wc + l15;
  const int rq = (lane >> 4) * 4;
  float b1c[4], w2c[4];
#pragma unroll
  for (int n = 0; n < 4; n++) { b1c[n] = b1[cb + n * 16]; w2c[n] = w2[cb + n * 16]; }
#pragma unroll
  for (int m = 0; m < 2; m++) {
#pragma unroll
    for (int r = 0; r < 4; r++) {
      int rl = wr + m * 16 + rq + r;      // 0..63, unique per (wv&1, m, rq, r)
      float s = 0.f;
#pragma unroll
      for (int n = 0; n < 4; n++) s += tanhf(acc[m][n][r] + b1c[n]) * w2c[n];
      s += __shfl_xor(s, 1, 64); s += __shfl_xor(s, 2, 64);
      s += __shfl_xor(s, 4, 64); s += __shfl_xor(s, 8, 64);
      if (l15 == 0) rsum[wv >> 1][rl] = s;   // col-wave index, accumulated below
    }
  }
  __syncthreads();
  if (tid < 64) {   // wave 0 exactly
    int grow = row0 + tid;
    float v = rsum[0][tid] + rsum[1][tid];
    float vA = (grow < CC) ? v : 0.f;
    float vB = (grow >= CC && grow < M) ? v : 0.f;
#pragma unroll
    for (int off = 32; off > 0; off >>= 1) {
      vA += __shfl_xor(vA, off, 64);
      vB += __shfl_xor(vB, off, 64);
    }
    if (tid == 0) {
      atomicAdd(scal + 0, vA);
      atomicAdd(scal + 1, vB);
    }
  }
}

// ---------------- batched CSR build (3 graphs), bucket-staged scatter ----------------
__global__ void k_hist3(const int* __restrict__ d0, const int* __restrict__ d1,
                        const int* __restrict__ d2, int* __restrict__ deg3) {
  int e = blockIdx.x * 256 + threadIdx.x;
  int g = blockIdx.y;
  const int* dst = (g == 0) ? d0 : (g == 1) ? d1 : d2;
  atomicAdd(deg3 + g * NN + dst[e], 1);
}

__global__ __launch_bounds__(1024) void k_scan3(const int* __restrict__ deg3,
                                                int* __restrict__ rowptr3,
                                                int* __restrict__ curB) {
  __shared__ int part[1024];
  const int g = blockIdx.x;
  const int* deg = deg3 + g * NN;
  int* rowptr = rowptr3 + g * (NN + 1);
  int tid = threadIdx.x;
  const int CH = 20;
  int base = tid * CH;
  int s = 0;
  for (int i = 0; i < CH; i++) { int idx = base + i; if (idx < NN) s += deg[idx]; }
  part[tid] = s;
  __syncthreads();
  for (int off = 1; off < 1024; off <<= 1) {
    int u = (tid >= off) ? part[tid - off] : 0;
    int v = part[tid];
    __syncthreads();
    part[tid] = u + v;
    __syncthreads();
  }
  int run = (tid == 0) ? 0 : part[tid - 1];
  for (int i = 0; i < CH; i++) {
    int idx = base + i;
    if (idx < NN) {
      rowptr[idx] = run;
      if ((idx & 255) == 0) curB[g * (NBKT + 1) + (idx >> 8)] = run;
      run += deg[idx];
    }
  }
  if (tid == 1023) rowptr[NN] = part[1023];
}

__global__ __launch_bounds__(1024) void k_coarse(const int* __restrict__ s0,
                                                 const int* __restrict__ s1,
                                                 const int* __restrict__ s2,
                                                 const int* __restrict__ d0,
                                                 const int* __restrict__ d1,
                                                 const int* __restrict__ d2,
                                                 int* __restrict__ curB,
                                                 unsigned* __restrict__ staging) {
  __shared__ int bcnt[NBKT];
  __shared__ int bbase[NBKT];
  int g = blockIdx.y;
  const int* src = (g == 0) ? s0 : (g == 1) ? s1 : s2;
  const int* dst = (g == 0) ? d0 : (g == 1) ? d1 : d2;
  int tid = threadIdx.x;
  if (tid < NBKT) bcnt[tid] = 0;
  __syncthreads();
  int e = blockIdx.x * 1024 + tid;
  bool val = e < NE;
  int b = 0, r = 0, sv = 0, dv = 0;
  if (val) {
    dv = dst[e]; sv = src[e];
    b = dv >> 8;
    r = atomicAdd(&bcnt[b], 1);
  }
  __syncthreads();
  if (tid < NBKT && bcnt[tid] > 0) bbase[tid] = atomicAdd(&curB[g * (NBKT + 1) + tid], bcnt[tid]);
  __syncthreads();
  if (val) staging[(size_t)g * NE + bbase[b] + r] = ((unsigned)sv << 8) | (unsigned)(dv & 255);
}

__global__ __launch_bounds__(1024) void k_fine(const int* __restrict__ rowptr3,
                                               const unsigned* __restrict__ staging,
                                               unsigned short* __restrict__ srcord3) {
  __shared__ int cur[256];
  int g = blockIdx.y, b = blockIdx.x;
  const int* rowptr = rowptr3 + g * (NN + 1);
  int n0 = b << 8;
  int tid = threadIdx.x;
  if (tid < 256) {
    int node = n0 + tid;
    cur[tid] = (node < NN) ? rowptr[node] : 0;
  }
  __syncthreads();
  int nend = n0 + 256; if (nend > NN) nend = NN;
  int start = rowptr[n0];
  int endp = rowptr[nend];
  for (int i = start + tid; i < endp; i += 1024) {
    unsigned u = staging[(size_t)g * NE + i];
    int nl = u & 255;
    int pos = atomicAdd(&cur[nl], 1);
    srcord3[(size_t)g * NE + pos] = (unsigned short)(u >> 8);
  }
}

// ---------------- FUSED softmax + gather agg + bias + elu, 3 graphs batched ----------------
__global__ __launch_bounds__(256) void k_aggf3(const int* __restrict__ rowptr3,
                                               const unsigned short* __restrict__ srcord3,
                                               const float* __restrict__ el3,
                                               const float* __restrict__ er3,
                                               const unsigned short* __restrict__ hb3,
                                               const float* __restrict__ b0p,
                                               const float* __restrict__ b1p,
                                               const float* __restrict__ b2p,
                                               unsigned short* __restrict__ ob3) {
  __shared__ float aS[4][64 * 8];
  __shared__ int sS[4][64];
  int g = blockIdx.y;
  const int* rowptr = rowptr3 + g * (NN + 1);
  const unsigned short* srcord = srcord3 + (size_t)g * NE;
  const float* el = el3 + (size_t)g * NN * NH;
  const float* er = er3 + (size_t)g * NN * NH;
  const unsigned short* hb = hb3 + (size_t)g * NN * NHD;
  const float* bias = (g == 0) ? b0p : (g == 1) ? b1p : b2p;
  unsigned short* ob = ob3 + (size_t)g * NN * NHD;

  int wv = threadIdx.x >> 6;
  int t = (blockIdx.x * 256 + threadIdx.x) >> 6;
  int lane = threadIdx.x & 63;
  int h = lane >> 3;
  int beg = rowptr[t], end = rowptr[t + 1];

  float4 er0 = ((const float4*)(er + (size_t)t * NH))[0];
  float4 er1 = ((const float4*)(er + (size_t)t * NH))[1];
  float erow[8] = {er0.x, er0.y, er0.z, er0.w, er1.x, er1.y, er1.z, er1.w};

  float acc[8] = {0.f, 0.f, 0.f, 0.f, 0.f, 0.f, 0.f, 0.f};
  float den = 0.f;

  for (int cbeg = beg; cbeg < end; cbeg += 64) {
    int cnt = end - cbeg; if (cnt > 64) cnt = 64;
    bool valid = lane < cnt;
    int pidx = cbeg + lane; if (pidx > end - 1) pidx = end - 1;
    int s = srcord[pidx];
    if (valid) {
      sS[wv][lane] = s;
      float4 a0 = ((const float4*)(el + (size_t)s * NH))[0];
      float4 a1 = ((const float4*)(el + (size_t)s * NH))[1];
      float v[8] = {a0.x + erow[0], a0.y + erow[1], a0.z + erow[2], a0.w + erow[3],
                    a1.x + erow[4], a1.y + erow[5], a1.z + erow[6], a1.w + erow[7]};
#pragma unroll
      for (int k = 0; k < 8; k++) {
        float x = v[k];
        x = x >= 0.f ? x : 0.2f * x;
        aS[wv][lane * 8 + k] = __expf(x);
      }
    }
    const unsigned short* hbl = hb + lane * 8;
    int q = 0;
    for (; q + 3 < cnt; q += 4) {
      int s0 = sS[wv][q], s1 = sS[wv][q + 1], s2 = sS[wv][q + 2], s3 = sS[wv][q + 3];
      float w0 = aS[wv][q * 8 + h];
      float w1 = aS[wv][(q + 1) * 8 + h];
      float w2 = aS[wv][(q + 2) * 8 + h];
      float w3 = aS[wv][(q + 3) * 8 + h];
      uint4 v0 = *(const uint4*)(hbl + (size_t)s0 * NHD);
      uint4 v1 = *(const uint4*)(hbl + (size_t)s1 * NHD);
      uint4 v2 = *(const uint4*)(hbl + (size_t)s2 * NHD);
      uint4 v3 = *(const uint4*)(hbl + (size_t)s3 * NHD);
      den += (w0 + w1) + (w2 + w3);
      acc[0] += w0 * bflo(v0.x); acc[1] += w0 * bfhi(v0.x);
      acc[2] += w0 * bflo(v0.y); acc[3] += w0 * bfhi(v0.y);
      acc[4] += w0 * bflo(v0.z); acc[5] += w0 * bfhi(v0.z);
      acc[6] += w0 * bflo(v0.w); acc[7] += w0 * bfhi(v0.w);
      acc[0] += w1 * bflo(v1.x); acc[1] += w1 * bfhi(v1.x);
      acc[2] += w1 * bflo(v1.y); acc[3] += w1 * bfhi(v1.y);
      acc[4] += w1 * bflo(v1.z); acc[5] += w1 * bfhi(v1.z);
      acc[6] += w1 * bflo(v1.w); acc[7] += w1 * bfhi(v1.w);
      acc[0] += w2 * bflo(v2.x); acc[1] += w2 * bfhi(v2.x);
      acc[2] += w2 * bflo(v2.y); acc[3] += w2 * bfhi(v2.y);
      acc[4] += w2 * bflo(v2.z); acc[5] += w2 * bfhi(v2.z);
      acc[6] += w2 * bflo(v2.w); acc[7] += w2 * bfhi(v2.w);
      acc[0] += w3 * bflo(v3.x); acc[1] += w3 * bfhi(v3.x);
      acc[2] += w3 * bflo(v3.y); acc[3] += w3 * bfhi(v3.y);
      acc[4] += w3 * bflo(v3.z); acc[5] += w3 * bfhi(v3.z);
      acc[6] += w3 * bflo(v3.w); acc[7] += w3 * bfhi(v3.w);
    }
    for (; q < cnt; q++) {
      int s0 = sS[wv][q];
      float w0 = aS[wv][q * 8 + h];
      uint4 v0 = *(const uint4*)(hbl + (size_t)s0 * NHD);
      den += w0;
      acc[0] += w0 * bflo(v0.x); acc[1] += w0 * bfhi(v0.x);
      acc[2] += w0 * bflo(v0.y); acc[3] += w0 * bfhi(v0.y);
      acc[4] += w0 * bflo(v0.z); acc[5] += w0 * bfhi(v0.z);
      acc[6] += w0 * bflo(v0.w); acc[7] += w0 * bfhi(v0.w);
    }
  }

  float dn = 1.f / fmaxf(den, 1e-9f);
  float4 b0 = ((const float4*)(bias + lane * 8))[0];
  float4 b1 = ((const float4*)(bias + lane * 8))[1];
  float r[8];
  r[0] = acc[0] * dn + b0.x; r[1] = acc[1] * dn + b0.y;
  r[2] = acc[2] * dn + b0.z; r[3] = acc[3] * dn + b0.w;
  r[4] = acc[4] * dn + b1.x; r[5] = acc[5] * dn + b1.y;
  r[6] = acc[6] * dn + b1.z; r[7] = acc[7] * dn + b1.w;
#pragma unroll
  for (int j = 0; j < 8; j++) r[j] = r[j] > 0.f ? r[j] : expm1f(r[j]);
  uint4 z;
  z.x = ((unsigned)f2bf(r[1]) << 16) | f2bf(r[0]);
  z.y = ((unsigned)f2bf(r[3]) << 16) | f2bf(r[2]);
  z.z = ((unsigned)f2bf(r[5]) << 16) | f2bf(r[4]);
  z.w = ((unsigned)f2bf(r[7]) << 16) | f2bf(r[6]);
  *(uint4*)(ob + (size_t)t * NHD + lane * 8) = z;
}

// stage 1: sound(bf16) = beta0*zA(bf16) + beta1*zB(bf16)
__global__ void k_combine_s1(const float* __restrict__ scal,
                             const unsigned short* __restrict__ zA,
                             const unsigned short* __restrict__ zB,
                             unsigned short* __restrict__ outb) {
  int i = blockIdx.x * 256 + threadIdx.x;   // grid exact CC*NHD/4
  float w0 = scal[0] * (1.f / CC), w1v = scal[1] * (1.f / CC);
  float mx = fmaxf(w0, w1v);
  float e0 = expf(w0 - mx), e1 = expf(w1v - mx);
  float inv = 1.f / (e0 + e1);
  float b0 = e0 * inv, b1v = e1 * inv;
  ushort4 a = ((const ushort4*)zA)[i];
  ushort4 b = ((const ushort4*)zB)[i];
  ushort4 z;
  z.x = f2bf(b0 * bf2f(a.x) + b1v * bf2f(b.x));
  z.y = f2bf(b0 * bf2f(a.y) + b1v * bf2f(b.y));
  z.z = f2bf(b0 * bf2f(a.z) + b1v * bf2f(b.z));
  z.w = f2bf(b0 * bf2f(a.w) + b1v * bf2f(b.w));
  ((ushort4*)outb)[i] = z;
}

// ---------------- fused stage-2 combine + final head-means (bf16 inputs) ----------------
__global__ void k_comb2_means(const float* __restrict__ scal,
                              const unsigned short* __restrict__ zsound,
                              const unsigned short* __restrict__ ob0,
                              const unsigned short* __restrict__ ob1,
                              const unsigned short* __restrict__ ob2,
                              float* __restrict__ outf,
                              float* __restrict__ m1, float* __restrict__ m2,
                              float* __restrict__ m3) {
  int idx = blockIdx.x * 256 + threadIdx.x;   // grid exact NN*64
  int n = idx >> 6, d = idx & 63;
  if (n < CC) {
    float w0 = scal[0] * (1.f / CC), w1v = scal[1] * (1.f / CC);
    float mx = fmaxf(w0, w1v);
    float e0 = expf(w0 - mx), e1 = expf(w1v - mx);
    float inv = 1.f / (e0 + e1);
    float b0 = e0 * inv, b1v = e1 * inv;
    const unsigned short* zs = zsound + (size_t)n * NHD + d;
    const unsigned short* p1 = ob1 + (size_t)n * NHD + d;
    float* po = outf + (size_t)n * NHD + d;
    float v = 0.f;
#pragma unroll
    for (int h = 0; h < 8; h++) {
      float r = b0 * bf2f(zs[h * 64]) + b1v * bf2f(p1[h * 64]);
      po[h * 64] = r;
      v += r;
    }
    v *= 0.125f;
    m1[idx] = v; m2[idx] = v; m3[idx] = v;
  } else {
    const unsigned short* p0 = ob0 + (size_t)n * NHD + d;
    const unsigned short* p1 = ob1 + (size_t)n * NHD + d;
    const unsigned short* p2 = ob2 + (size_t)n * NHD + d;
    float v0 = 0.f, v1 = 0.f, v2 = 0.f;
#pragma unroll
    for (int h = 0; h < 8; h++) {
      v0 += bf2f(p0[h * 64]); v1 += bf2f(p1[h * 64]); v2 += bf2f(p2[h * 64]);
    }
    m1[idx] = v0 * 0.125f; m2[idx] = v1 * 0.125f; m3[idx] = v2 * 0.125f;
  }
}

extern "C" void kernel_launch(void* const* d_in, const int* in_sizes, int n_in,
                              void* d_out, int out_size, void* d_ws, size_t ws_size,
                              hipStream_t stream) {
  (void)in_sizes; (void)n_in; (void)out_size; (void)ws_size;

  const float* feat[3]; const int* srcp[3]; const int* dstp[3];
  const float* Wp[3]; const float* alp[3]; const float* arp[3]; const float* bp[3];
  for (int g = 0; g < 3; g++) {
    const int base = g * 8;  // dict order: feat,src,dst,char,W,al,ar,b
    feat[g] = (const float*)d_in[base + 0];
    srcp[g] = (const int*)d_in[base + 1];
    dstp[g] = (const int*)d_in[base + 2];
    Wp[g]   = (const float*)d_in[base + 4];
    alp[g]  = (const float*)d_in[base + 5];
    arp[g]  = (const float*)d_in[base + 6];
    bp[g]   = (const float*)d_in[base + 7];
  }
  const float* sw1 = (const float*)d_in[24];
  const float* sb1 = (const float*)d_in[25];
  const float* sw2 = (const float*)d_in[26];
  const float* aw1 = (const float*)d_in[27];
  const float* ab1 = (const float*)d_in[28];
  const float* aw2 = (const float*)d_in[29];

  char* wsp = (char*)d_ws;
  auto alloc = [&](size_t bytes) {
    char* p = wsp;
    wsp += (bytes + 255) & ~(size_t)255;
    return p;
  };
  // total ~150 MB (proven-safe >= 229 MB from round 2)
  unsigned short* ob3 = (unsigned short*)alloc((size_t)3 * NN * NHD * 2);   // 61.5 MB
  unsigned short* hb3 = (unsigned short*)alloc((size_t)3 * NN * NHD * 2);   // 61.5 MB
  unsigned short* wtb3 = (unsigned short*)alloc((size_t)3 * WTB_SZ * 2);
  unsigned short* w1tb2 = (unsigned short*)alloc((size_t)2 * W1TB_SZ * 2);
  unsigned short* sound = (unsigned short*)alloc((size_t)CC * NHD * 2);
  float* el3 = (float*)alloc((size_t)3 * NN * NH * 4);
  float* er3 = (float*)alloc((size_t)3 * NN * NH * 4);
  float* scal = (float*)alloc(256);
  int* deg3 = (int*)alloc((size_t)3 * NN * 4);
  int* rowptr3 = (int*)alloc((size_t)3 * (NN + 1) * 4 + 64);
  int* curB = (int*)alloc((size_t)3 * (NBKT + 1) * 4);
  unsigned* staging = (unsigned*)alloc((size_t)3 * NE * 4);
  unsigned short* srcord3 = (unsigned short*)alloc((size_t)3 * NE * 2);

  unsigned short* ob0 = ob3;
  unsigned short* ob1 = ob3 + (size_t)NN * NHD;
  unsigned short* ob2 = ob3 + (size_t)2 * NN * NHD;

  float* outf = (float*)d_out;
  float* outm1 = outf + (size_t)CC * NHD;
  float* outm2 = outm1 + (size_t)NN * ND;
  float* outm3 = outm2 + (size_t)NN * ND;

  // ---- prep + CSR build (5 dispatches) ----
  const int PREP_T = 3 * WTB_SZ + 2 * W1TB_SZ + 3 * NN + 4;
  k_prep<<<(PREP_T + 255) / 256, 256, 0, stream>>>(Wp[0], Wp[1], Wp[2], sw1, aw1,
                                                   wtb3, w1tb2, deg3, scal);
  k_hist3<<<dim3(NE / 256, 3), 256, 0, stream>>>(dstp[0], dstp[1], dstp[2], deg3);
  k_scan3<<<3, 1024, 0, stream>>>(deg3, rowptr3, curB);
  k_coarse<<<dim3((NE + 1023) / 1024, 3), 1024, 0, stream>>>(
      srcp[0], srcp[1], srcp[2], dstp[0], dstp[1], dstp[2], curB, staging);
  k_fine<<<dim3(NBKT, 3), 1024, 0, stream>>>(rowptr3, staging, srcord3);

  // ---- all 3 GAT layers batched: one GEMM launch + one agg launch ----
  k_gemm_gat3<<<3 * GB, 256, 0, stream>>>(feat[0], feat[1], feat[2], wtb3, hb3,
                                          alp[0], alp[1], alp[2], arp[0], arp[1], arp[2],
                                          el3, er3);
  k_aggf3<<<dim3(NN * 64 / 256, 3), 256, 0, stream>>>(rowptr3, srcord3, el3, er3, hb3,
                                                      bp[0], bp[1], bp[2], ob3);

  // ---- semantic stage 1: rows<CC from ob0, rows>=CC from ob2 -> sound ----
  k_gemm_sem64<<<(2 * CC + 63) / 64, 256, 0, stream>>>(ob0, ob2, w1tb2, sb1, sw2, scal);
  k_combine_s1<<<CC * NHD / 4 / 256, 256, 0, stream>>>(scal, ob0, ob2, sound);

  // ---- semantic stage 2: rows<CC from sound, rows>=CC from ob1 -> combine+means ----
  k_gemm_sem64<<<(2 * CC + 63) / 64, 256, 0, stream>>>(sound, ob1, w1tb2 + W1TB_SZ, ab1, aw2, scal + 2);
  k_comb2_means<<<NN * 64 / 256, 256, 0, stream>>>(scal + 2, sound, ob0, ob1, ob2,
                                                   outf, outm1, outm2, outm3);
}